// Round 17
// baseline (302.706 us; speedup 1.0000x reference)
//
#include <hip/hip_runtime.h>
#include <hip/hip_bf16.h>

#define NTOK 65536
#define DD 256
#define FF 1024
#define EE 8
#define BSTRIDE 12288
#define CHUNK_US 16384             // 32KB chunk image in ushorts

typedef short bh8 __attribute__((ext_vector_type(8)));
typedef float f4v __attribute__((ext_vector_type(4)));

__device__ __forceinline__ unsigned rotl32(unsigned v, int d) {
  return (v << d) | (v >> (32 - d));
}

// JAX threefry2x32, 20 rounds. key = jax.random.key(42) -> (0, 42).
__device__ __forceinline__ unsigned jax_random_bits32(unsigned c0, unsigned c1) {
  const unsigned k0 = 0u, k1 = 42u;
  const unsigned k2 = 0x1BD11BDAu ^ k0 ^ k1;
  unsigned x0 = c0 + k0, x1 = c1 + k1;
#define TFR(r) { x0 += x1; x1 = rotl32(x1, (r)); x1 ^= x0; }
  TFR(13) TFR(15) TFR(26) TFR(6)
  x0 += k1; x1 += k2 + 1u;
  TFR(17) TFR(29) TFR(16) TFR(24)
  x0 += k2; x1 += k0 + 2u;
  TFR(13) TFR(15) TFR(26) TFR(6)
  x0 += k0; x1 += k1 + 3u;
  TFR(17) TFR(29) TFR(16) TFR(24)
  x0 += k1; x1 += k2 + 4u;
  TFR(13) TFR(15) TFR(26) TFR(6)
  x0 += k2; x1 += k0 + 5u;
#undef TFR
  return x0 ^ x1;
}

__device__ __forceinline__ ushort f2bf(float f) {
  union { float f; unsigned u; } c; c.f = f;
  unsigned r = c.u + 0x7fffu + ((c.u >> 16) & 1u);
  return (ushort)(r >> 16);
}

__device__ __forceinline__ unsigned pack2(float a, float b) {
  return (unsigned)f2bf(a) | ((unsigned)f2bf(b) << 16);
}

// ---------------- gate + route (+ optional x -> bf16 copy) ----------------
__global__ __launch_bounds__(1024) void gate_route3(
    const float* __restrict__ x, const float* __restrict__ gw,
    const float* __restrict__ gb, int* __restrict__ counts,
    int* __restrict__ buckets, ushort* __restrict__ xbf) {
  __shared__ float gwt[EE * DD];
  __shared__ int hist[EE], sbase[EE];
  __shared__ unsigned char chs[64];
  __shared__ short lps[64];

  const int tid = threadIdx.x;
  if (tid < EE) hist[tid] = 0;
  for (int i = tid; i < DD * EE; i += 1024) {
    const int d = i >> 3, e = i & 7;
    gwt[e * DD + d] = gw[i];
  }
  __syncthreads();

  const int lane = tid & 63;
  const int wave = tid >> 6;
  const int grp = lane >> 4;
  const int gl = lane & 15;
  const int slot = wave * 4 + grp;
  const int t = blockIdx.x * 64 + slot;

  float acc[EE] = {0.f, 0.f, 0.f, 0.f, 0.f, 0.f, 0.f, 0.f};
  const float* xr = x + (size_t)t * DD;
#pragma unroll
  for (int j = 0; j < 4; ++j) {
    const int d0 = j * 64 + gl * 4;
    const float4 xv = *reinterpret_cast<const float4*>(xr + d0);
    if (xbf != nullptr) {
      ushort4 xb;
      xb.x = f2bf(xv.x); xb.y = f2bf(xv.y); xb.z = f2bf(xv.z); xb.w = f2bf(xv.w);
      *reinterpret_cast<ushort4*>(xbf + (size_t)t * DD + d0) = xb;
    }
#pragma unroll
    for (int e = 0; e < EE; ++e) {
      const float4 g = *reinterpret_cast<const float4*>(&gwt[e * DD + d0]);
      acc[e] = fmaf(xv.x, g.x, acc[e]);
      acc[e] = fmaf(xv.y, g.y, acc[e]);
      acc[e] = fmaf(xv.z, g.z, acc[e]);
      acc[e] = fmaf(xv.w, g.w, acc[e]);
    }
  }
#pragma unroll
  for (int off = 8; off >= 1; off >>= 1)
#pragma unroll
    for (int e = 0; e < EE; ++e) acc[e] += __shfl_xor(acc[e], off);

  const int e = gl & 7;
  float logit = 0.f;
#pragma unroll
  for (int q = 0; q < EE; ++q) logit = (e == q) ? acc[q] : logit;
  logit += gb[e];

  const unsigned bits = jax_random_bits32(0u, (unsigned)(t * EE + e));
  const float f = __uint_as_float((bits >> 9) | 0x3f800000u) - 1.0f;
  const float u = fmaxf(1.17549435e-38f, f);
  float val = -logf(-logf(u)) + logit;
  int idx = e;
#pragma unroll
  for (int off = 4; off > 0; off >>= 1) {
    const float ov = __shfl_xor(val, off);
    const int oi = __shfl_xor(idx, off);
    if (ov > val || (ov == val && oi < idx)) { val = ov; idx = oi; }
  }
  if (gl == 0) {
    const int lp = atomicAdd(&hist[idx], 1);
    chs[slot] = (unsigned char)idx;
    lps[slot] = (short)lp;
  }
  __syncthreads();
  if (tid < EE) sbase[tid] = atomicAdd(&counts[tid], hist[tid]);
  __syncthreads();
  if (tid < 64) {
    const int ee = chs[tid];
    const int p = sbase[ee] + lps[tid];
    if (p < BSTRIDE) buckets[ee * BSTRIDE + p] = blockIdx.x * 64 + tid;
  }
}

// ---------------- weight prep: swizzled LDS-image layouts (proven v6-v11) ----------------
// w1s[e][fc][32KB]: (fl, d) @ byte (fl*512 + d*2) ^ ((fl&31)<<4)
__global__ __launch_bounds__(256) void prep_w1s(
    const float* __restrict__ w1, ushort* __restrict__ w1s) {
  __shared__ float ts[64][65];
  const int e = blockIdx.z;
  const int f0 = blockIdx.x * 64, d0 = blockIdx.y * 64;
  const int tx = threadIdx.x, ty = threadIdx.y;
  const float* s = w1 + (size_t)e * DD * FF;
  char* dimg = (char*)(w1s + (size_t)e * 16 * CHUNK_US + blockIdx.x * CHUNK_US);
#pragma unroll
  for (int i = 0; i < 16; ++i)
    ts[ty * 16 + i][tx] = s[(size_t)(d0 + ty * 16 + i) * FF + f0 + tx];
  __syncthreads();
#pragma unroll
  for (int i = 0; i < 16; ++i) {
    const int fl = ty * 16 + i;
    const int byte = ((fl * 512 + (d0 + tx) * 2)) ^ ((fl & 31) << 4);
    *reinterpret_cast<ushort*>(dimg + byte) = f2bf(ts[tx][fl]);
  }
}

// w2s[e][fc][32KB]: (d, fl) @ byte (d*128 + fl*2) ^ ((d&31)<<4)
__global__ __launch_bounds__(256) void prep_w2s(
    const float* __restrict__ w2, ushort* __restrict__ w2s) {
  __shared__ float ts[64][65];
  const int e = blockIdx.z;
  const int d0 = blockIdx.x * 64, f0 = blockIdx.y * 64;
  const int tx = threadIdx.x, ty = threadIdx.y;
  const float* s = w2 + (size_t)e * FF * DD;
  char* dimg = (char*)(w2s + (size_t)e * 16 * CHUNK_US + blockIdx.y * CHUNK_US);
#pragma unroll
  for (int i = 0; i < 16; ++i)
    ts[ty * 16 + i][tx] = s[(size_t)(f0 + ty * 16 + i) * DD + d0 + tx];
  __syncthreads();
#pragma unroll
  for (int i = 0; i < 16; ++i) {
    const int d = d0 + ty * 16 + i;
    const int byte = ((d * 128 + tx * 2)) ^ ((d & 31) << 4);
    *reinterpret_cast<ushort*>(dimg + byte) = f2bf(ts[tx][ty * 16 + i]);
  }
}

// stage one 32KB image with 8 waves: 4 issues x 64 lanes x 16B, linear LDS dest
__device__ __forceinline__ void stage32k(const ushort* g, ushort* l, int wid, int lane) {
  const ushort* gs = g + wid * 2048 + lane * 8;
  ushort* ls = l + wid * 2048;
#pragma unroll
  for (int i = 0; i < 4; ++i)
    __builtin_amdgcn_global_load_lds(
        (const __attribute__((address_space(1))) void*)(gs + i * 512),
        (__attribute__((address_space(3))) void*)(ls + i * 512), 16, 0, 0);
}

// ---------------- split kernel A: H = relu(Xg @ W1 + b1) ----------------
// Block (expert, m-tile 128, f-chunk 64): stage 32KB W1 image ONCE, X in regs,
// 256 MFMAs, 1 barrier. TLP (8192 active blocks, ~4/CU) hides all latency.
// Wave (fp=wid>>2, mg=wid&3): f-tiles {2fp,2fp+1}, m-tiles {mg, mg+4}.
__global__ __launch_bounds__(512, 4) void gemm1_split(
    const ushort* __restrict__ xbf, const ushort* __restrict__ w1s,
    const float* __restrict__ b1, const int* __restrict__ counts,
    const int* __restrict__ buckets, ushort* __restrict__ H) {
  const int e = blockIdx.x & 7;
  const int tile = blockIdx.x >> 3;
  const int fc = blockIdx.y;
  const int cnt = min(counts[e], BSTRIDE);
  const int m0 = tile * 128;
  if (m0 >= cnt) return;

  __shared__ ushort W1b[CHUNK_US];   // 32KB

  const int tid = threadIdx.x;
  const int lane = tid & 63;
  const int wid = tid >> 6;
  const int l15 = lane & 15;
  const int q = lane >> 4;
  const int fp = wid >> 2;
  const int mg = wid & 3;

  stage32k(w1s + ((size_t)e * 16 + fc) * CHUNK_US, W1b, wid, lane);

  // X B-frags + tokens for m-tiles mg, mg+4
  int tokx[2];
  bh8 xf[2][8];
#pragma unroll
  for (int i = 0; i < 2; ++i) {
    const int mxi = m0 + (mg + 4 * i) * 16 + l15;
    tokx[i] = buckets[e * BSTRIDE + (mxi < cnt ? mxi : cnt - 1)];
    const ushort* xp = xbf + (size_t)tokx[i] * DD + q * 8;
#pragma unroll
    for (int dks = 0; dks < 8; ++dks)
      xf[i][dks] = *reinterpret_cast<const bh8*>(xp + dks * 32);
  }

  __syncthreads();   // W1 image staged (the block's ONLY barrier)

  const char* wb = reinterpret_cast<const char*>(W1b);
  f4v hacc[2][2] = {};
  const int fl0 = (2 * fp) * 16 + l15;
  const int fl1 = (2 * fp + 1) * 16 + l15;
#pragma unroll
  for (int dks = 0; dks < 8; ++dks) {
    const int co = 64 * dks + 16 * q;
    const bh8 a0 = *reinterpret_cast<const bh8*>(
        wb + ((fl0 * 512 + co) ^ ((fl0 & 31) << 4)));
    const bh8 a1 = *reinterpret_cast<const bh8*>(
        wb + ((fl1 * 512 + co) ^ ((fl1 & 31) << 4)));
    hacc[0][0] = __builtin_amdgcn_mfma_f32_16x16x32_bf16(a0, xf[0][dks], hacc[0][0], 0, 0, 0);
    hacc[0][1] = __builtin_amdgcn_mfma_f32_16x16x32_bf16(a0, xf[1][dks], hacc[0][1], 0, 0, 0);
    hacc[1][0] = __builtin_amdgcn_mfma_f32_16x16x32_bf16(a1, xf[0][dks], hacc[1][0], 0, 0, 0);
    hacc[1][1] = __builtin_amdgcn_mfma_f32_16x16x32_bf16(a1, xf[1][dks], hacc[1][1], 0, 0, 0);
  }

  // bias + relu + pack -> H[tok][f] (D layout: f = t*16 + 4q + r, m = l15)
#pragma unroll
  for (int th = 0; th < 2; ++th) {
    const int ft = 2 * fp + th;
    const float4 bv = *reinterpret_cast<const float4*>(
        b1 + e * FF + fc * 64 + ft * 16 + 4 * q);
#pragma unroll
    for (int i = 0; i < 2; ++i) {
      const f4v& ha = hacc[th][i];
      uint2 wv;
      wv.x = pack2(fmaxf(ha[0] + bv.x, 0.f), fmaxf(ha[1] + bv.y, 0.f));
      wv.y = pack2(fmaxf(ha[2] + bv.z, 0.f), fmaxf(ha[3] + bv.w, 0.f));
      *reinterpret_cast<uint2*>(
          H + (size_t)tokx[i] * FF + fc * 64 + ft * 16 + 4 * q) = wv;
    }
  }
}

// ---------------- split kernel B: out = H @ W2 + b2 ----------------
// Block (expert, m-tile 64): K-loop over 16 f-chunks; W2 image double-buffered
// (1 barrier/chunk); H A-frags straight from global (contiguous 16B).
// Wave (mh=wid>>1, dh=wid&1): m-tile mh, d-half dh (8 d-tiles).
__global__ __launch_bounds__(512, 4) void gemm2_split(
    const ushort* __restrict__ H, const ushort* __restrict__ w2s,
    const float* __restrict__ b2, const int* __restrict__ counts,
    const int* __restrict__ buckets, float* __restrict__ out) {
  const int e = blockIdx.x & 7;
  const int tile = blockIdx.x >> 3;
  const int cnt = min(counts[e], BSTRIDE);
  const int m0 = tile * 64;
  if (m0 >= cnt) return;

  __shared__ ushort W2b[2][CHUNK_US];  // 64KB
  __shared__ int toks[64];

  const int tid = threadIdx.x;
  const int lane = tid & 63;
  const int wid = tid >> 6;
  const int l15 = lane & 15;
  const int q = lane >> 4;
  const int mh = wid >> 1;            // m-tile 0..3
  const int dh = wid & 1;             // d-half 0..1

  if (tid < 64) {
    const int i = m0 + tid;
    toks[tid] = buckets[e * BSTRIDE + (i < cnt ? i : cnt - 1)];
  }

  const ushort* w2g = w2s + (size_t)e * 16 * CHUNK_US;
  stage32k(w2g, W2b[0], wid, lane);

  // A-frag row token (row m = l15 of m-tile mh)
  const int mxi = m0 + mh * 16 + l15;
  const int tokA = buckets[e * BSTRIDE + (mxi < cnt ? mxi : cnt - 1)];
  const ushort* hp = H + (size_t)tokA * FF + q * 8;

  __syncthreads();   // prologue stage drained

  f4v yacc[8] = {};  // 8 d-tiles x 4

#pragma unroll 1
  for (int fc = 0; fc < 16; ++fc) {
    const int p = fc & 1;
    if (fc < 15)
      stage32k(w2g + (size_t)(fc + 1) * CHUNK_US, W2b[p ^ 1], wid, lane);

    const char* wb = reinterpret_cast<const char*>(W2b[p]);
#pragma unroll
    for (int ks = 0; ks < 2; ++ks) {
      const bh8 af = *reinterpret_cast<const bh8*>(hp + fc * 64 + ks * 32);
      const int co = ks * 64 + q * 16;
#pragma unroll
      for (int dt = 0; dt < 8; ++dt) {
        const int d = dh * 128 + dt * 16 + l15;
        const bh8 b = *reinterpret_cast<const bh8*>(
            wb + ((d * 128 + co) ^ ((d & 31) << 4)));
        yacc[dt] = __builtin_amdgcn_mfma_f32_16x16x32_bf16(af, b, yacc[dt], 0, 0, 0);
      }
    }
    __syncthreads();   // buf[p] reads done; stage(fc+1) drained
  }

  // epilogue: + b2, scatter. D: col d = dh*128+dt*16+l15, row m_loc = 4q+r.
#pragma unroll
  for (int dt = 0; dt < 8; ++dt) {
    const int d = dh * 128 + dt * 16 + l15;
    const float b2v = b2[e * DD + d];
#pragma unroll
    for (int r = 0; r < 4; ++r) {
      const int m = mh * 16 + 4 * q + r;
      if (m0 + m < cnt)
        out[(size_t)toks[m] * DD + d] = yacc[dt][r] + b2v;
    }
  }
}

// ---------------- fused FFN v10 (middle fallback, proven 139us) ----------------
__global__ __launch_bounds__(512, 4) void ffn_mfma10(
    const ushort* __restrict__ xbf, const ushort* __restrict__ w1s,
    const float* __restrict__ b1, const ushort* __restrict__ w2s,
    const float* __restrict__ b2, const int* __restrict__ counts,
    const int* __restrict__ buckets, float* __restrict__ out) {
  const int e = blockIdx.x & 7;
  const int tile = blockIdx.x >> 3;
  const int cnt = min(counts[e], BSTRIDE);
  const int m0 = tile * 64;
  if (m0 >= cnt) return;

  __shared__ ushort W1b[CHUNK_US];
  __shared__ ushort W2b[CHUNK_US];
  __shared__ ushort Hb[4096];

  const int tid = threadIdx.x;
  const int lane = tid & 63;
  const int wid = tid >> 6;
  const int l15 = lane & 15;
  const int q = lane >> 4;
  const int fp = wid >> 2;
  const int mt = wid & 3;
  const int dh = wid >> 2;

  const ushort* w1g = w1s + (size_t)e * 16 * CHUNK_US;
  const ushort* w2g = w2s + (size_t)e * 16 * CHUNK_US;

  stage32k(w1g, W1b, wid, lane);
  stage32k(w2g, W2b, wid, lane);

  const int mxi = m0 + mt * 16 + l15;
  const int tokx = buckets[e * BSTRIDE + (mxi < cnt ? mxi : cnt - 1)];
  const ushort* xp = xbf + (size_t)tokx * DD + q * 8;
  bh8 xf[8];
#pragma unroll
  for (int dks = 0; dks < 8; ++dks)
    xf[dks] = *reinterpret_cast<const bh8*>(xp + dks * 32);

  __syncthreads();

  f4v yacc[8] = {};

#pragma unroll 1
  for (int c = 0; c < 16; ++c) {
    {
      const char* wb = reinterpret_cast<const char*>(W1b);
      f4v h0 = {}, h1 = {};
      const int fl0 = (2 * fp) * 16 + l15;
      const int fl1 = (2 * fp + 1) * 16 + l15;
#pragma unroll
      for (int dks = 0; dks < 8; ++dks) {
        const int co = (32 * dks + 8 * q) * 2;
        const bh8 a0 = *reinterpret_cast<const bh8*>(
            wb + ((fl0 * 512 + co) ^ ((fl0 & 31) << 4)));
        const bh8 a1 = *reinterpret_cast<const bh8*>(
            wb + ((fl1 * 512 + co) ^ ((fl1 & 31) << 4)));
        h0 = __builtin_amdgcn_mfma_f32_16x16x32_bf16(a0, xf[dks], h0, 0, 0, 0);
        h1 = __builtin_amdgcn_mfma_f32_16x16x32_bf16(a1, xf[dks], h1, 0, 0, 0);
      }
      char* hbb = reinterpret_cast<char*>(Hb);
#pragma unroll
      for (int th = 0; th < 2; ++th) {
        const int t = 2 * fp + th;
        const float4 bv = *reinterpret_cast<const float4*>(
            b1 + e * FF + c * 64 + t * 16 + 4 * q);
        const f4v& ha = th ? h1 : h0;
        const float v0 = fmaxf(ha[0] + bv.x, 0.f);
        const float v1 = fmaxf(ha[1] + bv.y, 0.f);
        const float v2 = fmaxf(ha[2] + bv.z, 0.f);
        const float v3 = fmaxf(ha[3] + bv.w, 0.f);
        const int laneT = (2 * th + (q >> 1)) * 16 + l15;
        const int base = ((mt * 2 + fp) * 64 + laneT) * 16;
        *reinterpret_cast<unsigned*>(hbb + base + (((2 * q + 0) & 3) << 2)) = pack2(v0, v1);
        *reinterpret_cast<unsigned*>(hbb + base + (((2 * q + 1) & 3) << 2)) = pack2(v2, v3);
      }
    }
    __syncthreads();

    if (c < 15)
      stage32k(w1g + (size_t)(c + 1) * CHUNK_US, W1b, wid, lane);

    {
      const char* hbb = reinterpret_cast<const char*>(Hb);
      const char* wb = reinterpret_cast<const char*>(W2b);
#pragma unroll
      for (int ks = 0; ks < 2; ++ks) {
        const bh8 af = *reinterpret_cast<const bh8*>(
            hbb + ((mt * 2 + ks) * 64 + lane) * 16);
        const int co = (32 * ks + 8 * q) * 2;
#pragma unroll
        for (int dt = 0; dt < 8; ++dt) {
          const int d = (dh * 8 + dt) * 16 + l15;
          const bh8 b = *reinterpret_cast<const bh8*>(
              wb + ((d * 128 + co) ^ ((d & 31) << 4)));
          yacc[dt] = __builtin_amdgcn_mfma_f32_16x16x32_bf16(af, b, yacc[dt], 0, 0, 0);
        }
      }
    }
    __syncthreads();

    if (c < 15)
      stage32k(w2g + (size_t)(c + 1) * CHUNK_US, W2b, wid, lane);
  }

  int toks4[4];
#pragma unroll
  for (int r = 0; r < 4; ++r) {
    const int m = m0 + mt * 16 + 4 * q + r;
    toks4[r] = buckets[e * BSTRIDE + (m < cnt ? m : cnt - 1)];
  }
#pragma unroll
  for (int dt = 0; dt < 8; ++dt) {
    const int d = (dh * 8 + dt) * 16 + l15;
    const float b2v = b2[e * DD + d];
#pragma unroll
    for (int r = 0; r < 4; ++r) {
      const int m = mt * 16 + 4 * q + r;
      if (m0 + m < cnt)
        out[(size_t)toks4[r] * DD + d] = yacc[dt][r] + b2v;
    }
  }
}

// ---------------- fallback fp32 FFN (proven in round 1) ----------------
__global__ __launch_bounds__(512) void ffn_fp32(
    const float* __restrict__ x, const float* __restrict__ w1,
    const float* __restrict__ b1, const float* __restrict__ w2,
    const float* __restrict__ b2, const int* __restrict__ counts,
    const int* __restrict__ buckets, float* __restrict__ out, int bstride) {
  const int e = blockIdx.y;
  const int cnt = min(counts[e], bstride);
  const int m0 = blockIdx.x * 64;
  if (m0 >= cnt) return;

  __shared__ float Xt[DD][64];
  __shared__ float Ht[64][64];
  __shared__ int toks[64];

  const int tid = threadIdx.x;
  if (tid < 64) {
    const int i = m0 + tid;
    toks[tid] = buckets[e * bstride + (i < cnt ? i : cnt - 1)];
  }
  __syncthreads();

  for (int idx = tid; idx < 64 * (DD / 4); idx += 512) {
    const int r = idx >> 6;
    const int c4 = idx & 63;
    const float4 v = *reinterpret_cast<const float4*>(x + (size_t)toks[r] * DD + c4 * 4);
    Xt[c4 * 4 + 0][r] = v.x;
    Xt[c4 * 4 + 1][r] = v.y;
    Xt[c4 * 4 + 2][r] = v.z;
    Xt[c4 * 4 + 3][r] = v.w;
  }
  __syncthreads();

  const int fg = tid & 15;
  const int mg = tid >> 4;
  const int dc = tid & 63;
  const int mgrp = tid >> 6;

  float yacc[8][4];
#pragma unroll
  for (int i = 0; i < 8; ++i)
#pragma unroll
    for (int jj = 0; jj < 4; ++jj) yacc[i][jj] = 0.f;

  for (int fc0 = 0; fc0 < FF; fc0 += 64) {
    float hacc[2][4];
#pragma unroll
    for (int i = 0; i < 2; ++i)
#pragma unroll
      for (int jj = 0; jj < 4; ++jj) hacc[i][jj] = 0.f;

    const float* w1p = w1 + (size_t)e * DD * FF + fc0 + fg * 4;
    for (int d = 0; d < DD; ++d) {
      const float4 w = *reinterpret_cast<const float4*>(w1p + (size_t)d * FF);
      const float2 xv = *reinterpret_cast<const float2*>(&Xt[d][mg * 2]);
      const float ws[4] = {w.x, w.y, w.z, w.w};
      const float xl[2] = {xv.x, xv.y};
#pragma unroll
      for (int i = 0; i < 2; ++i)
#pragma unroll
        for (int jj = 0; jj < 4; ++jj)
          hacc[i][jj] = fmaf(xl[i], ws[jj], hacc[i][jj]);
    }
#pragma unroll
    for (int jj = 0; jj < 4; ++jj) {
      const float bb = b1[e * FF + fc0 + fg * 4 + jj];
      Ht[fg * 4 + jj][mg * 2 + 0] = fmaxf(hacc[0][jj] + bb, 0.f);
      Ht[fg * 4 + jj][mg * 2 + 1] = fmaxf(hacc[1][jj] + bb, 0.f);
    }
    __syncthreads();

    const float* w2p = w2 + (size_t)e * FF * DD + (size_t)fc0 * DD + dc * 4;
    for (int f = 0; f < 64; ++f) {
      const float4 w = *reinterpret_cast<const float4*>(w2p + (size_t)f * DD);
      const float4 h0 = *reinterpret_cast<const float4*>(&Ht[f][mgrp * 8]);
      const float4 h1 = *reinterpret_cast<const float4*>(&Ht[f][mgrp * 8 + 4]);
      const float hs[8] = {h0.x, h0.y, h0.z, h0.w, h1.x, h1.y, h1.z, h1.w};
      const float ws[4] = {w.x, w.y, w.z, w.w};
#pragma unroll
      for (int i = 0; i < 8; ++i)
#pragma unroll
        for (int jj = 0; jj < 4; ++jj)
          yacc[i][jj] = fmaf(hs[i], ws[jj], yacc[i][jj]);
    }
    __syncthreads();
  }

#pragma unroll
  for (int i = 0; i < 8; ++i) {
    const int r = mgrp * 8 + i;
    if (m0 + r < cnt) {
      float4 o;
      o.x = yacc[i][0] + b2[e * DD + dc * 4 + 0];
      o.y = yacc[i][1] + b2[e * DD + dc * 4 + 1];
      o.z = yacc[i][2] + b2[e * DD + dc * 4 + 2];
      o.w = yacc[i][3] + b2[e * DD + dc * 4 + 3];
      *reinterpret_cast<float4*>(out + (size_t)toks[r] * DD + dc * 4) = o;
    }
  }
}

extern "C" void kernel_launch(void* const* d_in, const int* in_sizes, int n_in,
                              void* d_out, int out_size, void* d_ws, size_t ws_size,
                              hipStream_t stream) {
  const float* x  = (const float*)d_in[0];
  const float* gw = (const float*)d_in[1];
  const float* gb = (const float*)d_in[2];
  const float* w1 = (const float*)d_in[3];
  const float* b1 = (const float*)d_in[4];
  const float* w2 = (const float*)d_in[5];
  const float* b2 = (const float*)d_in[6];
  float* out = (float*)d_out;

  // ws: counts@0 (4K) | buckets@4K (384K) | w1s@512K (4M) | w2s@4.5M (4M) |
  //     xbf@8.5M (32M) | H@40.5M (128M, split path only)
  int* counts = (int*)d_ws;
  int* buckets = (int*)((char*)d_ws + 4096);
  ushort* w1s = (ushort*)((char*)d_ws + 524288);
  ushort* w2s = (ushort*)((char*)d_ws + 524288 + 4194304);
  ushort* xbf = (ushort*)((char*)d_ws + 524288 + 2ull * 4194304);
  ushort* H   = (ushort*)((char*)d_ws + 524288 + 2ull * 4194304 + 33554432);
  const size_t need_mid = 524288 + 2ull * 4194304 + 33554432;
  const size_t need_big = need_mid + (size_t)NTOK * FF * 2;

  hipMemsetAsync(d_ws, 0, 4096, stream);

  if (ws_size >= need_mid) {
    hipLaunchKernelGGL(gate_route3, dim3(NTOK / 64), dim3(1024), 0, stream,
                       x, gw, gb, counts, buckets, xbf);
    hipLaunchKernelGGL(prep_w1s, dim3(FF / 64, DD / 64, EE), dim3(64, 4), 0, stream,
                       w1, w1s);
    hipLaunchKernelGGL(prep_w2s, dim3(DD / 64, FF / 64, EE), dim3(64, 4), 0, stream,
                       w2, w2s);
    if (ws_size >= need_big) {
      hipLaunchKernelGGL(gemm1_split, dim3((BSTRIDE / 128) * EE, 16), dim3(512), 0, stream,
                         xbf, w1s, b1, counts, buckets, H);
      hipLaunchKernelGGL(gemm2_split, dim3((BSTRIDE / 64) * EE), dim3(512), 0, stream,
                         H, w2s, b2, counts, buckets, out);
    } else {
      hipLaunchKernelGGL(ffn_mfma10, dim3((BSTRIDE / 64) * EE), dim3(512), 0, stream,
                         xbf, w1s, b1, w2s, b2, counts, buckets, out);
    }
  } else {
    hipLaunchKernelGGL(gate_route3, dim3(NTOK / 64), dim3(1024), 0, stream,
                       x, gw, gb, counts, buckets, (ushort*)nullptr);
    hipLaunchKernelGGL(ffn_fp32, dim3(NTOK / 64, EE), dim3(512), 0, stream,
                       x, w1, b1, w2, b2, counts, buckets, out, BSTRIDE);
  }
}

// Round 18
// 207.963 us; speedup vs baseline: 1.4556x; 1.4556x over previous
//
#include <hip/hip_runtime.h>
#include <hip/hip_bf16.h>

#define NTOK 65536
#define DD 256
#define FF 1024
#define EE 8
#define BSTRIDE 12288
#define MTILE 64
#define NTILES (BSTRIDE / MTILE)   // 192
#define CHUNK_US 16384             // 32KB chunk image in ushorts

typedef short bh8 __attribute__((ext_vector_type(8)));
typedef float f16v __attribute__((ext_vector_type(16)));

__device__ __forceinline__ unsigned rotl32(unsigned v, int d) {
  return (v << d) | (v >> (32 - d));
}

// JAX threefry2x32, 20 rounds. key = jax.random.key(42) -> (0, 42).
__device__ __forceinline__ unsigned jax_random_bits32(unsigned c0, unsigned c1) {
  const unsigned k0 = 0u, k1 = 42u;
  const unsigned k2 = 0x1BD11BDAu ^ k0 ^ k1;
  unsigned x0 = c0 + k0, x1 = c1 + k1;
#define TFR(r) { x0 += x1; x1 = rotl32(x1, (r)); x1 ^= x0; }
  TFR(13) TFR(15) TFR(26) TFR(6)
  x0 += k1; x1 += k2 + 1u;
  TFR(17) TFR(29) TFR(16) TFR(24)
  x0 += k2; x1 += k0 + 2u;
  TFR(13) TFR(15) TFR(26) TFR(6)
  x0 += k0; x1 += k1 + 3u;
  TFR(17) TFR(29) TFR(16) TFR(24)
  x0 += k1; x1 += k2 + 4u;
  TFR(13) TFR(15) TFR(26) TFR(6)
  x0 += k2; x1 += k0 + 5u;
#undef TFR
  return x0 ^ x1;
}

__device__ __forceinline__ ushort f2bf(float f) {
  union { float f; unsigned u; } c; c.f = f;
  unsigned r = c.u + 0x7fffu + ((c.u >> 16) & 1u);
  return (ushort)(r >> 16);
}

__device__ __forceinline__ unsigned pack2(float a, float b) {
  return (unsigned)f2bf(a) | ((unsigned)f2bf(b) << 16);
}

// ---------------- gate + route (+ optional x -> bf16 copy) ----------------
__global__ __launch_bounds__(1024) void gate_route3(
    const float* __restrict__ x, const float* __restrict__ gw,
    const float* __restrict__ gb, int* __restrict__ counts,
    int* __restrict__ buckets, ushort* __restrict__ xbf) {
  __shared__ float gwt[EE * DD];
  __shared__ int hist[EE], sbase[EE];
  __shared__ unsigned char chs[64];
  __shared__ short lps[64];

  const int tid = threadIdx.x;
  if (tid < EE) hist[tid] = 0;
  for (int i = tid; i < DD * EE; i += 1024) {
    const int d = i >> 3, e = i & 7;
    gwt[e * DD + d] = gw[i];
  }
  __syncthreads();

  const int lane = tid & 63;
  const int wave = tid >> 6;
  const int grp = lane >> 4;
  const int gl = lane & 15;
  const int slot = wave * 4 + grp;
  const int t = blockIdx.x * 64 + slot;

  float acc[EE] = {0.f, 0.f, 0.f, 0.f, 0.f, 0.f, 0.f, 0.f};
  const float* xr = x + (size_t)t * DD;
#pragma unroll
  for (int j = 0; j < 4; ++j) {
    const int d0 = j * 64 + gl * 4;
    const float4 xv = *reinterpret_cast<const float4*>(xr + d0);
    if (xbf != nullptr) {
      ushort4 xb;
      xb.x = f2bf(xv.x); xb.y = f2bf(xv.y); xb.z = f2bf(xv.z); xb.w = f2bf(xv.w);
      *reinterpret_cast<ushort4*>(xbf + (size_t)t * DD + d0) = xb;
    }
#pragma unroll
    for (int e = 0; e < EE; ++e) {
      const float4 g = *reinterpret_cast<const float4*>(&gwt[e * DD + d0]);
      acc[e] = fmaf(xv.x, g.x, acc[e]);
      acc[e] = fmaf(xv.y, g.y, acc[e]);
      acc[e] = fmaf(xv.z, g.z, acc[e]);
      acc[e] = fmaf(xv.w, g.w, acc[e]);
    }
  }
#pragma unroll
  for (int off = 8; off >= 1; off >>= 1)
#pragma unroll
    for (int e = 0; e < EE; ++e) acc[e] += __shfl_xor(acc[e], off);

  const int e = gl & 7;
  float logit = 0.f;
#pragma unroll
  for (int q = 0; q < EE; ++q) logit = (e == q) ? acc[q] : logit;
  logit += gb[e];

  const unsigned bits = jax_random_bits32(0u, (unsigned)(t * EE + e));
  const float f = __uint_as_float((bits >> 9) | 0x3f800000u) - 1.0f;
  const float u = fmaxf(1.17549435e-38f, f);
  float val = -logf(-logf(u)) + logit;
  int idx = e;
#pragma unroll
  for (int off = 4; off > 0; off >>= 1) {
    const float ov = __shfl_xor(val, off);
    const int oi = __shfl_xor(idx, off);
    if (ov > val || (ov == val && oi < idx)) { val = ov; idx = oi; }
  }
  if (gl == 0) {
    const int lp = atomicAdd(&hist[idx], 1);
    chs[slot] = (unsigned char)idx;
    lps[slot] = (short)lp;
  }
  __syncthreads();
  if (tid < EE) sbase[tid] = atomicAdd(&counts[tid], hist[tid]);
  __syncthreads();
  if (tid < 64) {
    const int ee = chs[tid];
    const int p = sbase[ee] + lps[tid];
    if (p < BSTRIDE) buckets[ee * BSTRIDE + p] = blockIdx.x * 64 + tid;
  }
}

// ---------------- weight prep: swizzled LDS-image layouts (proven v6-v11) ----------------
// w1s[e][fc][32KB]: (fl, d) @ byte (fl*512 + d*2) ^ ((fl&31)<<4)
__global__ __launch_bounds__(256) void prep_w1s(
    const float* __restrict__ w1, ushort* __restrict__ w1s) {
  __shared__ float ts[64][65];
  const int e = blockIdx.z;
  const int f0 = blockIdx.x * 64, d0 = blockIdx.y * 64;
  const int tx = threadIdx.x, ty = threadIdx.y;
  const float* s = w1 + (size_t)e * DD * FF;
  char* dimg = (char*)(w1s + (size_t)e * 16 * CHUNK_US + blockIdx.x * CHUNK_US);
#pragma unroll
  for (int i = 0; i < 16; ++i)
    ts[ty * 16 + i][tx] = s[(size_t)(d0 + ty * 16 + i) * FF + f0 + tx];
  __syncthreads();
#pragma unroll
  for (int i = 0; i < 16; ++i) {
    const int fl = ty * 16 + i;
    const int byte = ((fl * 512 + (d0 + tx) * 2)) ^ ((fl & 31) << 4);
    *reinterpret_cast<ushort*>(dimg + byte) = f2bf(ts[tx][fl]);
  }
}

// w2s[e][fc][32KB]: (d, fl) @ byte (d*128 + fl*2) ^ ((d&31)<<4)
__global__ __launch_bounds__(256) void prep_w2s(
    const float* __restrict__ w2, ushort* __restrict__ w2s) {
  __shared__ float ts[64][65];
  const int e = blockIdx.z;
  const int d0 = blockIdx.x * 64, f0 = blockIdx.y * 64;
  const int tx = threadIdx.x, ty = threadIdx.y;
  const float* s = w2 + (size_t)e * FF * DD;
  char* dimg = (char*)(w2s + (size_t)e * 16 * CHUNK_US + blockIdx.y * CHUNK_US);
#pragma unroll
  for (int i = 0; i < 16; ++i)
    ts[ty * 16 + i][tx] = s[(size_t)(f0 + ty * 16 + i) * DD + d0 + tx];
  __syncthreads();
#pragma unroll
  for (int i = 0; i < 16; ++i) {
    const int d = d0 + ty * 16 + i;
    const int byte = ((d * 128 + tx * 2)) ^ ((d & 31) << 4);
    *reinterpret_cast<ushort*>(dimg + byte) = f2bf(ts[tx][ty * 16 + i]);
  }
}

// stage one 32KB image with 4 waves (widx 0..3): 8 issues x 64 lanes x 16B
__device__ __forceinline__ void stage32k4(const ushort* g, ushort* l, int widx, int lane) {
  const ushort* gs = g + widx * 4096 + lane * 8;
  ushort* ls = l + widx * 4096;
#pragma unroll
  for (int i = 0; i < 8; ++i)
    __builtin_amdgcn_global_load_lds(
        (const __attribute__((address_space(1))) void*)(gs + i * 512),
        (__attribute__((address_space(3))) void*)(ls + i * 512), 16, 0, 0);
}

// ---------------- MFMA FFN v13: producer-consumer wave split ----------------
// waves 0-3 (G1): H(c+1) = relu(X @ W1(c+1) + b1)  [32x32 frags, X in regs]
// waves 4-7 (G2): yacc += H(c) @ W2(c)             [32x32 frags]
// One barrier per chunk; W1b/W2b/Hb all double-buffered (image k in buf[k&1]).
// G1 stages W1(c+2)->W1b[c&1]; G2 stages W2(c+1)->W2b[(c+1)&1]. All handoffs
// cross >=1 barrier (ownership verified). Role diversity -> MFMA/LDS/stage
// pipes of the two groups overlap (m114), setprio arbitrates (T5).
__global__ __launch_bounds__(512, 2) void ffn_pc(
    const ushort* __restrict__ xbf, const ushort* __restrict__ w1s,
    const float* __restrict__ b1, const ushort* __restrict__ w2s,
    const float* __restrict__ b2, const int* __restrict__ counts,
    const int* __restrict__ buckets, float* __restrict__ out) {
  const int e = blockIdx.x & 7;       // expert = id%8 -> pins images per-XCD L2
  const int tile = blockIdx.x >> 3;
  const int cnt = min(counts[e], BSTRIDE);
  const int m0 = tile * MTILE;
  if (m0 >= cnt) return;

  __shared__ ushort W1b[2][CHUNK_US];  // 64KB
  __shared__ ushort W2b[2][CHUNK_US];  // 64KB
  __shared__ ushort Hb[2][4096];       // 16KB: [M 2][K 4][lane 64][8] frag-ready
  __shared__ float Bb[FF];             // 4KB b1 (keeps loop free of vmem)
  __shared__ int toks[MTILE];

  const int tid = threadIdx.x;
  const int lane = tid & 63;
  const int wid = tid >> 6;            // 0..7
  const int l31 = lane & 31;
  const int h = lane >> 5;             // 0/1
  const bool isG1 = (wid < 4);
  const int g = wid >> 1;              // G1: f-half (wid 0-3 -> g = wid>>1 in 0..1)
  const int j = wid & 1;               // G1: m-half 0..1
  const int w2i = wid - 4;             // G2 index 0..3
  const int mh = w2i >> 1;             // G2: m-tile 0..1
  const int dq = w2i & 1;              // G2: d-half 0..1

  if (tid < MTILE) {
    const int i = m0 + tid;
    toks[tid] = buckets[e * BSTRIDE + (i < cnt ? i : cnt - 1)];
  }
  Bb[tid] = b1[e * FF + tid];
  Bb[tid + 512] = b1[e * FF + 512 + tid];

  const ushort* w1g = w1s + (size_t)e * 16 * CHUNK_US;
  const ushort* w2g = w2s + (size_t)e * 16 * CHUNK_US;

  // prologue staging: W1(0)->W1b[0], W1(1)->W1b[1] (G1); W2(0)->W2b[0] (G2)
  if (isG1) {
    stage32k4(w1g, W1b[0], wid, lane);
    stage32k4(w1g + CHUNK_US, W1b[1], wid, lane);
  } else {
    stage32k4(w2g, W2b[0], w2i, lane);
  }

  // G1: X fragments for m-half j (32 rows), 16 ksteps x 16B = 32 VGPR.
  bh8 xf[16];
  if (isG1) {
    const int mxi = m0 + j * 32 + l31;
    const int tokx = buckets[e * BSTRIDE + (mxi < cnt ? mxi : cnt - 1)];
    const ushort* xp = xbf + (size_t)tokx * DD + h * 8;
#pragma unroll
    for (int ks = 0; ks < 16; ++ks)
      xf[ks] = *reinterpret_cast<const bh8*>(xp + ks * 16);
  }

  const int fl = g * 32 + l31;         // G1 A-frag row (f-local)
  const int w1x = (fl & 31) << 4;

  __syncthreads();                     // prologue staging drained

  // G1 chunk-compute: H(cc) from W1b[cc&1] -> Hb[cc&1] (v7-verified algebra)
  auto g1_compute = [&](int cc) {
    const char* wb = reinterpret_cast<const char*>(W1b[cc & 1]);
    f16v hacc = {};
    __builtin_amdgcn_s_setprio(1);
#pragma unroll
    for (int ks = 0; ks < 16; ++ks) {
      const int byte = (fl * 512 + ks * 32 + h * 16) ^ w1x;
      const bh8 a = *reinterpret_cast<const bh8*>(wb + byte);
      hacc = __builtin_amdgcn_mfma_f32_32x32x16_bf16(a, xf[ks], hacc, 0, 0, 0);
    }
    __builtin_amdgcn_s_setprio(0);
    float hv[16];
#pragma unroll
    for (int q = 0; q < 4; ++q) {
      const float4 bv = *reinterpret_cast<const float4*>(
          &Bb[cc * 64 + g * 32 + q * 8 + 4 * h]);
      hv[q * 4 + 0] = fmaxf(hacc[q * 4 + 0] + bv.x, 0.f);
      hv[q * 4 + 1] = fmaxf(hacc[q * 4 + 1] + bv.y, 0.f);
      hv[q * 4 + 2] = fmaxf(hacc[q * 4 + 2] + bv.z, 0.f);
      hv[q * 4 + 3] = fmaxf(hacc[q * 4 + 3] + bv.w, 0.f);
    }
    char* hbb = reinterpret_cast<char*>(Hb[cc & 1]);
#pragma unroll
    for (int ksl = 0; ksl < 2; ++ksl) {
      const unsigned plo0 = pack2(hv[8 * ksl + 0], hv[8 * ksl + 1]);
      const unsigned plo1 = pack2(hv[8 * ksl + 2], hv[8 * ksl + 3]);
      const unsigned phi0 = pack2(hv[8 * ksl + 4], hv[8 * ksl + 5]);
      const unsigned phi1 = pack2(hv[8 * ksl + 6], hv[8 * ksl + 7]);
      const unsigned r0 = (unsigned)__shfl_xor((int)(h ? plo0 : phi0), 32);
      const unsigned r1 = (unsigned)__shfl_xor((int)(h ? plo1 : phi1), 32);
      uint4 w;
      w.x = h ? r0 : plo0;
      w.y = h ? r1 : plo1;
      w.z = h ? phi0 : r0;
      w.w = h ? phi1 : r1;
      const int K = g * 2 + ksl;
      *reinterpret_cast<uint4*>(hbb + (j * 4 + K) * 1024 + lane * 16) = w;
    }
  };

  f16v yacc[4] = {};                   // G2: 4 d-tiles x 16 (64 AGPR)

  // G2 chunk-compute: yacc += Hb[c&1] @ W2b[c&1] (v7-verified patterns)
  auto g2_compute = [&](int c) {
    const char* hbb = reinterpret_cast<const char*>(Hb[c & 1]);
    const char* wb = reinterpret_cast<const char*>(W2b[c & 1]);
    __builtin_amdgcn_s_setprio(1);
#pragma unroll
    for (int K = 0; K < 4; ++K) {
      const bh8 hfa = *reinterpret_cast<const bh8*>(
          hbb + ((mh * 4 + K) * 64 + lane) * 16);
#pragma unroll
      for (int dt = 0; dt < 4; ++dt) {
        const int d = dq * 128 + dt * 32 + l31;
        const int byte = (d * 128 + K * 32 + h * 16) ^ ((d & 31) << 4);
        const bh8 b = *reinterpret_cast<const bh8*>(wb + byte);
        yacc[dt] = __builtin_amdgcn_mfma_f32_32x32x16_bf16(hfa, b, yacc[dt], 0, 0, 0);
      }
    }
    __builtin_amdgcn_s_setprio(0);
  };

  // prologue compute: H(0) (G1 only)
  if (isG1) g1_compute(0);
  __syncthreads();

#pragma unroll 1
  for (int c = 0; c < 16; ++c) {
    if (isG1) {
      if (c + 2 < 16)
        stage32k4(w1g + (size_t)(c + 2) * CHUNK_US, W1b[c & 1], wid, lane);
      if (c + 1 < 16)
        g1_compute(c + 1);
    } else {
      if (c + 1 < 16)
        stage32k4(w2g + (size_t)(c + 1) * CHUNK_US, W2b[(c + 1) & 1], w2i, lane);
      g2_compute(c);
    }
    __syncthreads();   // chunk boundary: all handoffs + own-stage drains
  }

  // epilogue (G2 waves only): + b2, scatter
  if (!isG1) {
#pragma unroll
    for (int dt = 0; dt < 4; ++dt) {
      const int d = dq * 128 + dt * 32 + l31;
      const float b2v = b2[e * DD + d];
#pragma unroll
      for (int r = 0; r < 16; ++r) {
        const int m = mh * 32 + (r & 3) + 8 * (r >> 2) + 4 * h;
        if (m0 + m < cnt)
          out[(size_t)toks[m] * DD + d] = yacc[dt][r] + b2v;
      }
    }
  }
}

// ---------------- fallback fp32 FFN (proven in round 1) ----------------
__global__ __launch_bounds__(512) void ffn_fp32(
    const float* __restrict__ x, const float* __restrict__ w1,
    const float* __restrict__ b1, const float* __restrict__ w2,
    const float* __restrict__ b2, const int* __restrict__ counts,
    const int* __restrict__ buckets, float* __restrict__ out, int bstride) {
  const int e = blockIdx.y;
  const int cnt = min(counts[e], bstride);
  const int m0 = blockIdx.x * 64;
  if (m0 >= cnt) return;

  __shared__ float Xt[DD][64];
  __shared__ float Ht[64][64];
  __shared__ int toks[64];

  const int tid = threadIdx.x;
  if (tid < 64) {
    const int i = m0 + tid;
    toks[tid] = buckets[e * bstride + (i < cnt ? i : cnt - 1)];
  }
  __syncthreads();

  for (int idx = tid; idx < 64 * (DD / 4); idx += 512) {
    const int r = idx >> 6;
    const int c4 = idx & 63;
    const float4 v = *reinterpret_cast<const float4*>(x + (size_t)toks[r] * DD + c4 * 4);
    Xt[c4 * 4 + 0][r] = v.x;
    Xt[c4 * 4 + 1][r] = v.y;
    Xt[c4 * 4 + 2][r] = v.z;
    Xt[c4 * 4 + 3][r] = v.w;
  }
  __syncthreads();

  const int fg = tid & 15;
  const int mg = tid >> 4;
  const int dc = tid & 63;
  const int mgrp = tid >> 6;

  float yacc[8][4];
#pragma unroll
  for (int i = 0; i < 8; ++i)
#pragma unroll
    for (int jj = 0; jj < 4; ++jj) yacc[i][jj] = 0.f;

  for (int fc0 = 0; fc0 < FF; fc0 += 64) {
    float hacc[2][4];
#pragma unroll
    for (int i = 0; i < 2; ++i)
#pragma unroll
      for (int jj = 0; jj < 4; ++jj) hacc[i][jj] = 0.f;

    const float* w1p = w1 + (size_t)e * DD * FF + fc0 + fg * 4;
    for (int d = 0; d < DD; ++d) {
      const float4 w = *reinterpret_cast<const float4*>(w1p + (size_t)d * FF);
      const float2 xv = *reinterpret_cast<const float2*>(&Xt[d][mg * 2]);
      const float ws[4] = {w.x, w.y, w.z, w.w};
      const float xl[2] = {xv.x, xv.y};
#pragma unroll
      for (int i = 0; i < 2; ++i)
#pragma unroll
        for (int jj = 0; jj < 4; ++jj)
          hacc[i][jj] = fmaf(xl[i], ws[jj], hacc[i][jj]);
    }
#pragma unroll
    for (int jj = 0; jj < 4; ++jj) {
      const float bb = b1[e * FF + fc0 + fg * 4 + jj];
      Ht[fg * 4 + jj][mg * 2 + 0] = fmaxf(hacc[0][jj] + bb, 0.f);
      Ht[fg * 4 + jj][mg * 2 + 1] = fmaxf(hacc[1][jj] + bb, 0.f);
    }
    __syncthreads();

    const float* w2p = w2 + (size_t)e * FF * DD + (size_t)fc0 * DD + dc * 4;
    for (int f = 0; f < 64; ++f) {
      const float4 w = *reinterpret_cast<const float4*>(w2p + (size_t)f * DD);
      const float4 h0 = *reinterpret_cast<const float4*>(&Ht[f][mgrp * 8]);
      const float4 h1 = *reinterpret_cast<const float4*>(&Ht[f][mgrp * 8 + 4]);
      const float hs[8] = {h0.x, h0.y, h0.z, h0.w, h1.x, h1.y, h1.z, h1.w};
      const float ws[4] = {w.x, w.y, w.z, w.w};
#pragma unroll
      for (int i = 0; i < 8; ++i)
#pragma unroll
        for (int jj = 0; jj < 4; ++jj)
          yacc[i][jj] = fmaf(hs[i], ws[jj], yacc[i][jj]);
    }
    __syncthreads();
  }

#pragma unroll
  for (int i = 0; i < 8; ++i) {
    const int r = mgrp * 8 + i;
    if (m0 + r < cnt) {
      float4 o;
      o.x = yacc[i][0] + b2[e * DD + dc * 4 + 0];
      o.y = yacc[i][1] + b2[e * DD + dc * 4 + 1];
      o.z = yacc[i][2] + b2[e * DD + dc * 4 + 2];
      o.w = yacc[i][3] + b2[e * DD + dc * 4 + 3];
      *reinterpret_cast<float4*>(out + (size_t)toks[r] * DD + dc * 4) = o;
    }
  }
}

extern "C" void kernel_launch(void* const* d_in, const int* in_sizes, int n_in,
                              void* d_out, int out_size, void* d_ws, size_t ws_size,
                              hipStream_t stream) {
  const float* x  = (const float*)d_in[0];
  const float* gw = (const float*)d_in[1];
  const float* gb = (const float*)d_in[2];
  const float* w1 = (const float*)d_in[3];
  const float* b1 = (const float*)d_in[4];
  const float* w2 = (const float*)d_in[5];
  const float* b2 = (const float*)d_in[6];
  float* out = (float*)d_out;

  // ws: counts@0 (4K) | buckets@4K (384K) | w1s@512K (4M) | w2s@4.5M (4M) | xbf@8.5M (32M)
  int* counts = (int*)d_ws;
  int* buckets = (int*)((char*)d_ws + 4096);
  ushort* w1s = (ushort*)((char*)d_ws + 524288);
  ushort* w2s = (ushort*)((char*)d_ws + 524288 + 4194304);
  ushort* xbf = (ushort*)((char*)d_ws + 524288 + 2ull * 4194304);
  const size_t need = 524288 + 2ull * 4194304 + (size_t)NTOK * DD * 2;

  hipMemsetAsync(d_ws, 0, 4096, stream);

  if (ws_size >= need) {
    hipLaunchKernelGGL(gate_route3, dim3(NTOK / 64), dim3(1024), 0, stream,
                       x, gw, gb, counts, buckets, xbf);
    hipLaunchKernelGGL(prep_w1s, dim3(FF / 64, DD / 64, EE), dim3(64, 4), 0, stream,
                       w1, w1s);
    hipLaunchKernelGGL(prep_w2s, dim3(DD / 64, FF / 64, EE), dim3(64, 4), 0, stream,
                       w2, w2s);
    hipLaunchKernelGGL(ffn_pc, dim3(NTILES * EE), dim3(512), 0, stream,
                       xbf, w1s, b1, w2s, b2, counts, buckets, out);
  } else {
    hipLaunchKernelGGL(gate_route3, dim3(NTOK / 64), dim3(1024), 0, stream,
                       x, gw, gb, counts, buckets, (ushort*)nullptr);
    hipLaunchKernelGGL(ffn_fp32, dim3(NTOK / 64, EE), dim3(512), 0, stream,
                       x, w1, b1, w2, b2, counts, buckets, out, BSTRIDE);
  }
}

// Round 19
// 205.350 us; speedup vs baseline: 1.4741x; 1.0127x over previous
//
#include <hip/hip_runtime.h>
#include <hip/hip_bf16.h>

#define NTOK 65536
#define DD 256
#define FF 1024
#define EE 8
#define BSTRIDE 12288
#define MTILE 128
#define NTILES (BSTRIDE / MTILE)   // 96
#define CHUNK_US 16384             // 32KB chunk image in ushorts

typedef short bh8 __attribute__((ext_vector_type(8)));
typedef float f16v __attribute__((ext_vector_type(16)));

#define PHASE_BAR() do { \
  asm volatile("s_waitcnt lgkmcnt(0)" ::: "memory"); \
  __builtin_amdgcn_s_barrier(); \
  __builtin_amdgcn_sched_barrier(0); \
} while (0)

__device__ __forceinline__ unsigned rotl32(unsigned v, int d) {
  return (v << d) | (v >> (32 - d));
}

// JAX threefry2x32, 20 rounds. key = jax.random.key(42) -> (0, 42).
__device__ __forceinline__ unsigned jax_random_bits32(unsigned c0, unsigned c1) {
  const unsigned k0 = 0u, k1 = 42u;
  const unsigned k2 = 0x1BD11BDAu ^ k0 ^ k1;
  unsigned x0 = c0 + k0, x1 = c1 + k1;
#define TFR(r) { x0 += x1; x1 = rotl32(x1, (r)); x1 ^= x0; }
  TFR(13) TFR(15) TFR(26) TFR(6)
  x0 += k1; x1 += k2 + 1u;
  TFR(17) TFR(29) TFR(16) TFR(24)
  x0 += k2; x1 += k0 + 2u;
  TFR(13) TFR(15) TFR(26) TFR(6)
  x0 += k0; x1 += k1 + 3u;
  TFR(17) TFR(29) TFR(16) TFR(24)
  x0 += k1; x1 += k2 + 4u;
  TFR(13) TFR(15) TFR(26) TFR(6)
  x0 += k2; x1 += k0 + 5u;
#undef TFR
  return x0 ^ x1;
}

__device__ __forceinline__ ushort f2bf(float f) {
  union { float f; unsigned u; } c; c.f = f;
  unsigned r = c.u + 0x7fffu + ((c.u >> 16) & 1u);
  return (ushort)(r >> 16);
}

__device__ __forceinline__ unsigned pack2(float a, float b) {
  return (unsigned)f2bf(a) | ((unsigned)f2bf(b) << 16);
}

// ---------------- gate + route (+ optional x -> bf16 copy) ----------------
__global__ __launch_bounds__(1024) void gate_route3(
    const float* __restrict__ x, const float* __restrict__ gw,
    const float* __restrict__ gb, int* __restrict__ counts,
    int* __restrict__ buckets, ushort* __restrict__ xbf) {
  __shared__ float gwt[EE * DD];
  __shared__ int hist[EE], sbase[EE];
  __shared__ unsigned char chs[64];
  __shared__ short lps[64];

  const int tid = threadIdx.x;
  if (tid < EE) hist[tid] = 0;
  for (int i = tid; i < DD * EE; i += 1024) {
    const int d = i >> 3, e = i & 7;
    gwt[e * DD + d] = gw[i];
  }
  __syncthreads();

  const int lane = tid & 63;
  const int wave = tid >> 6;
  const int grp = lane >> 4;
  const int gl = lane & 15;
  const int slot = wave * 4 + grp;
  const int t = blockIdx.x * 64 + slot;

  float acc[EE] = {0.f, 0.f, 0.f, 0.f, 0.f, 0.f, 0.f, 0.f};
  const float* xr = x + (size_t)t * DD;
#pragma unroll
  for (int j = 0; j < 4; ++j) {
    const int d0 = j * 64 + gl * 4;
    const float4 xv = *reinterpret_cast<const float4*>(xr + d0);
    if (xbf != nullptr) {
      ushort4 xb;
      xb.x = f2bf(xv.x); xb.y = f2bf(xv.y); xb.z = f2bf(xv.z); xb.w = f2bf(xv.w);
      *reinterpret_cast<ushort4*>(xbf + (size_t)t * DD + d0) = xb;
    }
#pragma unroll
    for (int e = 0; e < EE; ++e) {
      const float4 g = *reinterpret_cast<const float4*>(&gwt[e * DD + d0]);
      acc[e] = fmaf(xv.x, g.x, acc[e]);
      acc[e] = fmaf(xv.y, g.y, acc[e]);
      acc[e] = fmaf(xv.z, g.z, acc[e]);
      acc[e] = fmaf(xv.w, g.w, acc[e]);
    }
  }
#pragma unroll
  for (int off = 8; off >= 1; off >>= 1)
#pragma unroll
    for (int e = 0; e < EE; ++e) acc[e] += __shfl_xor(acc[e], off);

  const int e = gl & 7;
  float logit = 0.f;
#pragma unroll
  for (int q = 0; q < EE; ++q) logit = (e == q) ? acc[q] : logit;
  logit += gb[e];

  const unsigned bits = jax_random_bits32(0u, (unsigned)(t * EE + e));
  const float f = __uint_as_float((bits >> 9) | 0x3f800000u) - 1.0f;
  const float u = fmaxf(1.17549435e-38f, f);
  float val = -logf(-logf(u)) + logit;
  int idx = e;
#pragma unroll
  for (int off = 4; off > 0; off >>= 1) {
    const float ov = __shfl_xor(val, off);
    const int oi = __shfl_xor(idx, off);
    if (ov > val || (ov == val && oi < idx)) { val = ov; idx = oi; }
  }
  if (gl == 0) {
    const int lp = atomicAdd(&hist[idx], 1);
    chs[slot] = (unsigned char)idx;
    lps[slot] = (short)lp;
  }
  __syncthreads();
  if (tid < EE) sbase[tid] = atomicAdd(&counts[tid], hist[tid]);
  __syncthreads();
  if (tid < 64) {
    const int ee = chs[tid];
    const int p = sbase[ee] + lps[tid];
    if (p < BSTRIDE) buckets[ee * BSTRIDE + p] = blockIdx.x * 64 + tid;
  }
}

// ---------------- weight prep: swizzled LDS-image layouts (proven v6-v11) ----------------
__global__ __launch_bounds__(256) void prep_w1s(
    const float* __restrict__ w1, ushort* __restrict__ w1s) {
  __shared__ float ts[64][65];
  const int e = blockIdx.z;
  const int f0 = blockIdx.x * 64, d0 = blockIdx.y * 64;
  const int tx = threadIdx.x, ty = threadIdx.y;
  const float* s = w1 + (size_t)e * DD * FF;
  char* dimg = (char*)(w1s + (size_t)e * 16 * CHUNK_US + blockIdx.x * CHUNK_US);
#pragma unroll
  for (int i = 0; i < 16; ++i)
    ts[ty * 16 + i][tx] = s[(size_t)(d0 + ty * 16 + i) * FF + f0 + tx];
  __syncthreads();
#pragma unroll
  for (int i = 0; i < 16; ++i) {
    const int fl = ty * 16 + i;
    const int byte = ((fl * 512 + (d0 + tx) * 2)) ^ ((fl & 31) << 4);
    *reinterpret_cast<ushort*>(dimg + byte) = f2bf(ts[tx][fl]);
  }
}

__global__ __launch_bounds__(256) void prep_w2s(
    const float* __restrict__ w2, ushort* __restrict__ w2s) {
  __shared__ float ts[64][65];
  const int e = blockIdx.z;
  const int d0 = blockIdx.x * 64, f0 = blockIdx.y * 64;
  const int tx = threadIdx.x, ty = threadIdx.y;
  const float* s = w2 + (size_t)e * FF * DD;
  char* dimg = (char*)(w2s + (size_t)e * 16 * CHUNK_US + blockIdx.y * CHUNK_US);
#pragma unroll
  for (int i = 0; i < 16; ++i)
    ts[ty * 16 + i][tx] = s[(size_t)(f0 + ty * 16 + i) * DD + d0 + tx];
  __syncthreads();
#pragma unroll
  for (int i = 0; i < 16; ++i) {
    const int d = d0 + ty * 16 + i;
    const int byte = ((d * 128 + tx * 2)) ^ ((d & 31) << 4);
    *reinterpret_cast<ushort*>(dimg + byte) = f2bf(ts[tx][ty * 16 + i]);
  }
}

// stage a full 32KB image (8 waves x 4 x 16B) or a 16KB half (iters 2h..2h+1)
__device__ __forceinline__ void stage32k(const ushort* g, ushort* l, int wid, int lane) {
  const ushort* gs = g + wid * 2048 + lane * 8;
  ushort* ls = l + wid * 2048;
#pragma unroll
  for (int i = 0; i < 4; ++i)
    __builtin_amdgcn_global_load_lds(
        (const __attribute__((address_space(1))) void*)(gs + i * 512),
        (__attribute__((address_space(3))) void*)(ls + i * 512), 16, 0, 0);
}
__device__ __forceinline__ void stage16k(const ushort* g, ushort* l, int wid, int lane, int half) {
  const ushort* gs = g + wid * 2048 + lane * 8;
  ushort* ls = l + wid * 2048;
#pragma unroll
  for (int i = 2 * half; i < 2 * half + 2; ++i)
    __builtin_amdgcn_global_load_lds(
        (const __attribute__((address_space(1))) void*)(gs + i * 512),
        (__attribute__((address_space(3))) void*)(ls + i * 512), 16, 0, 0);
}

// ---------------- MFMA FFN v14: 5-phase fine-interleaved chunk (T3+T4+T5) ----------------
// Per chunk c (p=c&1), phases each closed by {lgkmcnt(0); s_barrier; sched_barrier}:
//  P1: issue 2x W1(c+1)->W1b[p^1] ; G1 MFMA ks0-7   (W1b[p] reads, X regs)
//  P2: issue 2x W1(c+1)           ; G1 MFMA ks8-15
//  P3: issue 4x W2(c+1)->W2b[p^1] ; H pack/ds_write ; vmcnt(8)  [W2(c) resident]
//  P4: G2 MFMA K0-1 (Hb + W2b[p])
//  P5: G2 MFMA K2-3 ; vmcnt(4)                       [W1(c+1) resident]
// Counted waits never drain the queue; 4 loads always in flight (m218/T4).
__global__ __launch_bounds__(512, 2) void ffn_8p(
    const ushort* __restrict__ xbf, const ushort* __restrict__ w1s,
    const float* __restrict__ b1, const ushort* __restrict__ w2s,
    const float* __restrict__ b2, const int* __restrict__ counts,
    const int* __restrict__ buckets, float* __restrict__ out) {
  const int e = blockIdx.x & 7;       // expert = id%8 -> pins images per-XCD L2
  const int tile = blockIdx.x >> 3;
  const int cnt = min(counts[e], BSTRIDE);
  const int m0 = tile * MTILE;
  if (m0 >= cnt) return;

  __shared__ ushort W1b[2][CHUNK_US];  // 64KB
  __shared__ ushort W2b[2][CHUNK_US];  // 64KB
  __shared__ ushort Hb[8192];          // 16KB: [M 4][K 4][lane 64][8] frag-ready
  __shared__ float Bb[FF];             // 4KB b1 (loop stays vmem-free)
  __shared__ int toks[MTILE];

  const int tid = threadIdx.x;
  const int lane = tid & 63;
  const int wid = tid >> 6;            // 0..7
  const int l31 = lane & 31;
  const int h = lane >> 5;             // 0/1
  const int g = wid & 1;               // G1: f-half
  const int j = wid >> 1;              // G1: m-block 0..3
  const int mh = wid >> 2;             // G2: m-half
  const int dq = wid & 3;              // G2: d-quarter

  if (tid < MTILE) {
    const int i = m0 + tid;
    toks[tid] = buckets[e * BSTRIDE + (i < cnt ? i : cnt - 1)];
  }
  Bb[tid] = b1[e * FF + tid];
  Bb[tid + 512] = b1[e * FF + 512 + tid];

  const ushort* w1g = w1s + (size_t)e * 16 * CHUNK_US;
  const ushort* w2g = w2s + (size_t)e * 16 * CHUNK_US;

  // prologue staging: chunk 0 into parity-0 buffers
  stage32k(w1g, W1b[0], wid, lane);
  stage32k(w2g, W2b[0], wid, lane);

  // X fragments for m-block j (32 rows), 16 ksteps x 16B (v7/v8-verified)
  const int mx = m0 + j * 32 + l31;
  const int tokx = buckets[e * BSTRIDE + (mx < cnt ? mx : cnt - 1)];
  const ushort* xp = xbf + (size_t)tokx * DD + h * 8;
  bh8 xf[16];
#pragma unroll
  for (int ks = 0; ks < 16; ++ks)
    xf[ks] = *reinterpret_cast<const bh8*>(xp + ks * 16);

  const int fl = g * 32 + l31;
  const int w1x = (fl & 31) << 4;
  __syncthreads();                     // full drain: vmcnt queue now empty

  f16v yacc[2][2] = {};

  // G1 half: accumulate 8 ksteps of chunk (reads W1b[p])
  auto g1_half = [&](const char* wb, bh8* xfp, f16v& hacc, int k0) {
    __builtin_amdgcn_s_setprio(1);
#pragma unroll
    for (int ks = 0; ks < 8; ++ks) {
      const int kk = k0 + ks;
      const int byte = (fl * 512 + kk * 32 + h * 16) ^ w1x;
      const bh8 a = *reinterpret_cast<const bh8*>(wb + byte);
      hacc = __builtin_amdgcn_mfma_f32_32x32x16_bf16(a, xfp[kk], hacc, 0, 0, 0);
    }
    __builtin_amdgcn_s_setprio(0);
  };

  // H pack (v7/v8-verified): bias+relu+bf16+shfl -> frag-ready Hb
  auto h_pack = [&](int cc, const f16v& hacc) {
    float hv[16];
#pragma unroll
    for (int q = 0; q < 4; ++q) {
      const float4 bv = *reinterpret_cast<const float4*>(
          &Bb[cc * 64 + g * 32 + q * 8 + 4 * h]);
      hv[q * 4 + 0] = fmaxf(hacc[q * 4 + 0] + bv.x, 0.f);
      hv[q * 4 + 1] = fmaxf(hacc[q * 4 + 1] + bv.y, 0.f);
      hv[q * 4 + 2] = fmaxf(hacc[q * 4 + 2] + bv.z, 0.f);
      hv[q * 4 + 3] = fmaxf(hacc[q * 4 + 3] + bv.w, 0.f);
    }
    char* hbb = reinterpret_cast<char*>(Hb);
#pragma unroll
    for (int ksl = 0; ksl < 2; ++ksl) {
      const unsigned plo0 = pack2(hv[8 * ksl + 0], hv[8 * ksl + 1]);
      const unsigned plo1 = pack2(hv[8 * ksl + 2], hv[8 * ksl + 3]);
      const unsigned phi0 = pack2(hv[8 * ksl + 4], hv[8 * ksl + 5]);
      const unsigned phi1 = pack2(hv[8 * ksl + 6], hv[8 * ksl + 7]);
      const unsigned r0 = (unsigned)__shfl_xor((int)(h ? plo0 : phi0), 32);
      const unsigned r1 = (unsigned)__shfl_xor((int)(h ? plo1 : phi1), 32);
      uint4 w;
      w.x = h ? r0 : plo0;
      w.y = h ? r1 : plo1;
      w.z = h ? phi0 : r0;
      w.w = h ? phi1 : r1;
      const int K = g * 2 + ksl;
      *reinterpret_cast<uint4*>(hbb + (j * 4 + K) * 1024 + lane * 16) = w;
    }
  };

  // G2 half: 2 K-slots (reads Hb + W2b[p])
  auto g2_half = [&](const char* wb, int K0) {
    const char* hbb = reinterpret_cast<const char*>(Hb);
    __builtin_amdgcn_s_setprio(1);
#pragma unroll
    for (int Ki = 0; Ki < 2; ++Ki) {
      const int K = K0 + Ki;
      const bh8 a0 = *reinterpret_cast<const bh8*>(
          hbb + ((mh * 2 + 0) * 4 + K) * 1024 + lane * 16);
      const bh8 a1 = *reinterpret_cast<const bh8*>(
          hbb + ((mh * 2 + 1) * 4 + K) * 1024 + lane * 16);
#pragma unroll
      for (int dt = 0; dt < 2; ++dt) {
        const int d = dq * 64 + dt * 32 + l31;
        const int byte = (d * 128 + K * 32 + h * 16) ^ ((d & 31) << 4);
        const bh8 b = *reinterpret_cast<const bh8*>(wb + byte);
        yacc[0][dt] = __builtin_amdgcn_mfma_f32_32x32x16_bf16(a0, b, yacc[0][dt], 0, 0, 0);
        yacc[1][dt] = __builtin_amdgcn_mfma_f32_32x32x16_bf16(a1, b, yacc[1][dt], 0, 0, 0);
      }
    }
    __builtin_amdgcn_s_setprio(0);
  };

#pragma unroll 1
  for (int c = 0; c < 15; ++c) {
    const int p = c & 1;
    const char* w1rb = reinterpret_cast<const char*>(W1b[p]);
    const char* w2rb = reinterpret_cast<const char*>(W2b[p]);
    f16v hacc = {};
    // P1
    stage16k(w1g + (size_t)(c + 1) * CHUNK_US, W1b[p ^ 1], wid, lane, 0);
    g1_half(w1rb, xf, hacc, 0);
    PHASE_BAR();
    // P2
    stage16k(w1g + (size_t)(c + 1) * CHUNK_US, W1b[p ^ 1], wid, lane, 1);
    g1_half(w1rb, xf, hacc, 8);
    PHASE_BAR();
    // P3
    stage32k(w2g + (size_t)(c + 1) * CHUNK_US, W2b[p ^ 1], wid, lane);
    h_pack(c, hacc);
    asm volatile("s_waitcnt vmcnt(8)" ::: "memory");
    PHASE_BAR();
    // P4
    g2_half(w2rb, 0);
    PHASE_BAR();
    // P5
    g2_half(w2rb, 2);
    asm volatile("s_waitcnt vmcnt(4)" ::: "memory");
    PHASE_BAR();
  }
  // peeled chunk 15 (p = 1, no stages)
  {
    const char* w1rb = reinterpret_cast<const char*>(W1b[1]);
    const char* w2rb = reinterpret_cast<const char*>(W2b[1]);
    f16v hacc = {};
    g1_half(w1rb, xf, hacc, 0);
    PHASE_BAR();
    g1_half(w1rb, xf, hacc, 8);
    PHASE_BAR();
    h_pack(15, hacc);
    asm volatile("s_waitcnt vmcnt(0)" ::: "memory");
    PHASE_BAR();
    g2_half(w2rb, 0);
    PHASE_BAR();
    g2_half(w2rb, 2);
  }

  // epilogue: + b2, scatter (v7/v8-verified mapping)
#pragma unroll
  for (int mb = 0; mb < 2; ++mb) {
#pragma unroll
    for (int dt = 0; dt < 2; ++dt) {
      const int d = dq * 64 + dt * 32 + l31;
      const float b2v = b2[e * DD + d];
#pragma unroll
      for (int r = 0; r < 16; ++r) {
        const int m = mh * 64 + mb * 32 + (r & 3) + 8 * (r >> 2) + 4 * h;
        if (m0 + m < cnt)
          out[(size_t)toks[m] * DD + d] = yacc[mb][dt][r] + b2v;
      }
    }
  }
}

// ---------------- fallback fp32 FFN (proven in round 1) ----------------
__global__ __launch_bounds__(512) void ffn_fp32(
    const float* __restrict__ x, const float* __restrict__ w1,
    const float* __restrict__ b1, const float* __restrict__ w2,
    const float* __restrict__ b2, const int* __restrict__ counts,
    const int* __restrict__ buckets, float* __restrict__ out, int bstride) {
  const int e = blockIdx.y;
  const int cnt = min(counts[e], bstride);
  const int m0 = blockIdx.x * 64;
  if (m0 >= cnt) return;

  __shared__ float Xt[DD][64];
  __shared__ float Ht[64][64];
  __shared__ int toks[64];

  const int tid = threadIdx.x;
  if (tid < 64) {
    const int i = m0 + tid;
    toks[tid] = buckets[e * bstride + (i < cnt ? i : cnt - 1)];
  }
  __syncthreads();

  for (int idx = tid; idx < 64 * (DD / 4); idx += 512) {
    const int r = idx >> 6;
    const int c4 = idx & 63;
    const float4 v = *reinterpret_cast<const float4*>(x + (size_t)toks[r] * DD + c4 * 4);
    Xt[c4 * 4 + 0][r] = v.x;
    Xt[c4 * 4 + 1][r] = v.y;
    Xt[c4 * 4 + 2][r] = v.z;
    Xt[c4 * 4 + 3][r] = v.w;
  }
  __syncthreads();

  const int fg = tid & 15;
  const int mg = tid >> 4;
  const int dc = tid & 63;
  const int mgrp = tid >> 6;

  float yacc[8][4];
#pragma unroll
  for (int i = 0; i < 8; ++i)
#pragma unroll
    for (int jj = 0; jj < 4; ++jj) yacc[i][jj] = 0.f;

  for (int fc0 = 0; fc0 < FF; fc0 += 64) {
    float hacc[2][4];
#pragma unroll
    for (int i = 0; i < 2; ++i)
#pragma unroll
      for (int jj = 0; jj < 4; ++jj) hacc[i][jj] = 0.f;

    const float* w1p = w1 + (size_t)e * DD * FF + fc0 + fg * 4;
    for (int d = 0; d < DD; ++d) {
      const float4 w = *reinterpret_cast<const float4*>(w1p + (size_t)d * FF);
      const float2 xv = *reinterpret_cast<const float2*>(&Xt[d][mg * 2]);
      const float ws[4] = {w.x, w.y, w.z, w.w};
      const float xl[2] = {xv.x, xv.y};
#pragma unroll
      for (int i = 0; i < 2; ++i)
#pragma unroll
        for (int jj = 0; jj < 4; ++jj)
          hacc[i][jj] = fmaf(xl[i], ws[jj], hacc[i][jj]);
    }
#pragma unroll
    for (int jj = 0; jj < 4; ++jj) {
      const float bb = b1[e * FF + fc0 + fg * 4 + jj];
      Ht[fg * 4 + jj][mg * 2 + 0] = fmaxf(hacc[0][jj] + bb, 0.f);
      Ht[fg * 4 + jj][mg * 2 + 1] = fmaxf(hacc[1][jj] + bb, 0.f);
    }
    __syncthreads();

    const float* w2p = w2 + (size_t)e * FF * DD + (size_t)fc0 * DD + dc * 4;
    for (int f = 0; f < 64; ++f) {
      const float4 w = *reinterpret_cast<const float4*>(w2p + (size_t)f * DD);
      const float4 h0 = *reinterpret_cast<const float4*>(&Ht[f][mgrp * 8]);
      const float4 h1 = *reinterpret_cast<const float4*>(&Ht[f][mgrp * 8 + 4]);
      const float hs[8] = {h0.x, h0.y, h0.z, h0.w, h1.x, h1.y, h1.z, h1.w};
      const float ws[4] = {w.x, w.y, w.z, w.w};
#pragma unroll
      for (int i = 0; i < 8; ++i)
#pragma unroll
        for (int jj = 0; jj < 4; ++jj)
          yacc[i][jj] = fmaf(hs[i], ws[jj], yacc[i][jj]);
    }
    __syncthreads();
  }

#pragma unroll
  for (int i = 0; i < 8; ++i) {
    const int r = mgrp * 8 + i;
    if (m0 + r < cnt) {
      float4 o;
      o.x = yacc[i][0] + b2[e * DD + dc * 4 + 0];
      o.y = yacc[i][1] + b2[e * DD + dc * 4 + 1];
      o.z = yacc[i][2] + b2[e * DD + dc * 4 + 2];
      o.w = yacc[i][3] + b2[e * DD + dc * 4 + 3];
      *reinterpret_cast<float4*>(out + (size_t)toks[r] * DD + dc * 4) = o;
    }
  }
}

extern "C" void kernel_launch(void* const* d_in, const int* in_sizes, int n_in,
                              void* d_out, int out_size, void* d_ws, size_t ws_size,
                              hipStream_t stream) {
  const float* x  = (const float*)d_in[0];
  const float* gw = (const float*)d_in[1];
  const float* gb = (const float*)d_in[2];
  const float* w1 = (const float*)d_in[3];
  const float* b1 = (const float*)d_in[4];
  const float* w2 = (const float*)d_in[5];
  const float* b2 = (const float*)d_in[6];
  float* out = (float*)d_out;

  // ws: counts@0 (4K) | buckets@4K (384K) | w1s@512K (4M) | w2s@4.5M (4M) | xbf@8.5M (32M)
  int* counts = (int*)d_ws;
  int* buckets = (int*)((char*)d_ws + 4096);
  ushort* w1s = (ushort*)((char*)d_ws + 524288);
  ushort* w2s = (ushort*)((char*)d_ws + 524288 + 4194304);
  ushort* xbf = (ushort*)((char*)d_ws + 524288 + 2ull * 4194304);
  const size_t need = 524288 + 2ull * 4194304 + (size_t)NTOK * DD * 2;

  hipMemsetAsync(d_ws, 0, 4096, stream);

  if (ws_size >= need) {
    hipLaunchKernelGGL(gate_route3, dim3(NTOK / 64), dim3(1024), 0, stream,
                       x, gw, gb, counts, buckets, xbf);
    hipLaunchKernelGGL(prep_w1s, dim3(FF / 64, DD / 64, EE), dim3(64, 4), 0, stream,
                       w1, w1s);
    hipLaunchKernelGGL(prep_w2s, dim3(DD / 64, FF / 64, EE), dim3(64, 4), 0, stream,
                       w2, w2s);
    hipLaunchKernelGGL(ffn_8p, dim3(NTILES * EE), dim3(512), 0, stream,
                       xbf, w1s, b1, w2s, b2, counts, buckets, out);
  } else {
    hipLaunchKernelGGL(gate_route3, dim3(NTOK / 64), dim3(1024), 0, stream,
                       x, gw, gb, counts, buckets, (ushort*)nullptr);
    hipLaunchKernelGGL(ffn_fp32, dim3(NTOK / 64, EE), dim3(512), 0, stream,
                       x, w1, b1, w2, b2, counts, buckets, out, BSTRIDE);
  }
}

// Round 20
// 167.497 us; speedup vs baseline: 1.8072x; 1.2260x over previous
//
#include <hip/hip_runtime.h>
#include <hip/hip_bf16.h>

#define NTOK 65536
#define DD 256
#define FF 1024
#define EE 8
#define BSTRIDE 12288
#define MTILE 64
#define NTILES (BSTRIDE / MTILE)   // 192
#define CHUNK_US 16384             // 32KB chunk image in ushorts

typedef short bh8 __attribute__((ext_vector_type(8)));
typedef float f4v __attribute__((ext_vector_type(4)));

__device__ __forceinline__ unsigned rotl32(unsigned v, int d) {
  return (v << d) | (v >> (32 - d));
}

// JAX threefry2x32, 20 rounds. key = jax.random.key(42) -> (0, 42).
// partitionable: counter for flat element j is (hi,lo)=(0,j); out = x0 ^ x1.
__device__ __forceinline__ unsigned jax_random_bits32(unsigned c0, unsigned c1) {
  const unsigned k0 = 0u, k1 = 42u;
  const unsigned k2 = 0x1BD11BDAu ^ k0 ^ k1;
  unsigned x0 = c0 + k0, x1 = c1 + k1;
#define TFR(r) { x0 += x1; x1 = rotl32(x1, (r)); x1 ^= x0; }
  TFR(13) TFR(15) TFR(26) TFR(6)
  x0 += k1; x1 += k2 + 1u;
  TFR(17) TFR(29) TFR(16) TFR(24)
  x0 += k2; x1 += k0 + 2u;
  TFR(13) TFR(15) TFR(26) TFR(6)
  x0 += k0; x1 += k1 + 3u;
  TFR(17) TFR(29) TFR(16) TFR(24)
  x0 += k1; x1 += k2 + 4u;
  TFR(13) TFR(15) TFR(26) TFR(6)
  x0 += k2; x1 += k0 + 5u;
#undef TFR
  return x0 ^ x1;
}

__device__ __forceinline__ ushort f2bf(float f) {
  union { float f; unsigned u; } c; c.f = f;
  unsigned r = c.u + 0x7fffu + ((c.u >> 16) & 1u);
  return (ushort)(r >> 16);
}

__device__ __forceinline__ unsigned pack2(float a, float b) {
  return (unsigned)f2bf(a) | ((unsigned)f2bf(b) << 16);
}

// ---------------- gate + route (+ optional x -> bf16 copy) ----------------
__global__ __launch_bounds__(1024) void gate_route3(
    const float* __restrict__ x, const float* __restrict__ gw,
    const float* __restrict__ gb, int* __restrict__ counts,
    int* __restrict__ buckets, ushort* __restrict__ xbf) {
  __shared__ float gwt[EE * DD];
  __shared__ int hist[EE], sbase[EE];
  __shared__ unsigned char chs[64];
  __shared__ short lps[64];

  const int tid = threadIdx.x;
  if (tid < EE) hist[tid] = 0;
  for (int i = tid; i < DD * EE; i += 1024) {
    const int d = i >> 3, e = i & 7;
    gwt[e * DD + d] = gw[i];
  }
  __syncthreads();

  const int lane = tid & 63;
  const int wave = tid >> 6;
  const int grp = lane >> 4;
  const int gl = lane & 15;
  const int slot = wave * 4 + grp;
  const int t = blockIdx.x * 64 + slot;

  float acc[EE] = {0.f, 0.f, 0.f, 0.f, 0.f, 0.f, 0.f, 0.f};
  const float* xr = x + (size_t)t * DD;
#pragma unroll
  for (int j = 0; j < 4; ++j) {
    const int d0 = j * 64 + gl * 4;
    const float4 xv = *reinterpret_cast<const float4*>(xr + d0);
    if (xbf != nullptr) {   // fused bf16 conversion of x (consumed by ffn_mfma10)
      ushort4 xb;
      xb.x = f2bf(xv.x); xb.y = f2bf(xv.y); xb.z = f2bf(xv.z); xb.w = f2bf(xv.w);
      *reinterpret_cast<ushort4*>(xbf + (size_t)t * DD + d0) = xb;
    }
#pragma unroll
    for (int e = 0; e < EE; ++e) {
      const float4 g = *reinterpret_cast<const float4*>(&gwt[e * DD + d0]);
      acc[e] = fmaf(xv.x, g.x, acc[e]);
      acc[e] = fmaf(xv.y, g.y, acc[e]);
      acc[e] = fmaf(xv.z, g.z, acc[e]);
      acc[e] = fmaf(xv.w, g.w, acc[e]);
    }
  }
#pragma unroll
  for (int off = 8; off >= 1; off >>= 1)
#pragma unroll
    for (int e = 0; e < EE; ++e) acc[e] += __shfl_xor(acc[e], off);

  const int e = gl & 7;
  float logit = 0.f;
#pragma unroll
  for (int q = 0; q < EE; ++q) logit = (e == q) ? acc[q] : logit;
  logit += gb[e];

  const unsigned bits = jax_random_bits32(0u, (unsigned)(t * EE + e));
  const float f = __uint_as_float((bits >> 9) | 0x3f800000u) - 1.0f;
  const float u = fmaxf(1.17549435e-38f, f);
  float val = -logf(-logf(u)) + logit;
  int idx = e;
#pragma unroll
  for (int off = 4; off > 0; off >>= 1) {
    const float ov = __shfl_xor(val, off);
    const int oi = __shfl_xor(idx, off);
    if (ov > val || (ov == val && oi < idx)) { val = ov; idx = oi; }
  }
  if (gl == 0) {
    const int lp = atomicAdd(&hist[idx], 1);
    chs[slot] = (unsigned char)idx;
    lps[slot] = (short)lp;
  }
  __syncthreads();
  if (tid < EE) sbase[tid] = atomicAdd(&counts[tid], hist[tid]);
  __syncthreads();
  if (tid < 64) {
    const int ee = chs[tid];
    const int p = sbase[ee] + lps[tid];
    if (p < BSTRIDE) buckets[ee * BSTRIDE + p] = blockIdx.x * 64 + tid;
  }
}

// ---------------- weight prep: swizzled LDS-image layouts (proven v6-v11) ----------------
// w1s[e][fc][32KB]: (fl, d) @ byte (fl*512 + d*2) ^ ((fl&31)<<4)
__global__ __launch_bounds__(256) void prep_w1s(
    const float* __restrict__ w1, ushort* __restrict__ w1s) {
  __shared__ float ts[64][65];
  const int e = blockIdx.z;
  const int f0 = blockIdx.x * 64, d0 = blockIdx.y * 64;
  const int tx = threadIdx.x, ty = threadIdx.y;
  const float* s = w1 + (size_t)e * DD * FF;
  char* dimg = (char*)(w1s + (size_t)e * 16 * CHUNK_US + blockIdx.x * CHUNK_US);
#pragma unroll
  for (int i = 0; i < 16; ++i)
    ts[ty * 16 + i][tx] = s[(size_t)(d0 + ty * 16 + i) * FF + f0 + tx];
  __syncthreads();
#pragma unroll
  for (int i = 0; i < 16; ++i) {
    const int fl = ty * 16 + i;
    const int byte = ((fl * 512 + (d0 + tx) * 2)) ^ ((fl & 31) << 4);
    *reinterpret_cast<ushort*>(dimg + byte) = f2bf(ts[tx][fl]);
  }
}

// w2s[e][fc][32KB]: (d, fl) @ byte (d*128 + fl*2) ^ ((d&31)<<4)
__global__ __launch_bounds__(256) void prep_w2s(
    const float* __restrict__ w2, ushort* __restrict__ w2s) {
  __shared__ float ts[64][65];
  const int e = blockIdx.z;
  const int d0 = blockIdx.x * 64, f0 = blockIdx.y * 64;
  const int tx = threadIdx.x, ty = threadIdx.y;
  const float* s = w2 + (size_t)e * FF * DD;
  char* dimg = (char*)(w2s + (size_t)e * 16 * CHUNK_US + blockIdx.y * CHUNK_US);
#pragma unroll
  for (int i = 0; i < 16; ++i)
    ts[ty * 16 + i][tx] = s[(size_t)(f0 + ty * 16 + i) * DD + d0 + tx];
  __syncthreads();
#pragma unroll
  for (int i = 0; i < 16; ++i) {
    const int d = d0 + ty * 16 + i;
    const int byte = ((d * 128 + tx * 2)) ^ ((d & 31) << 4);
    *reinterpret_cast<ushort*>(dimg + byte) = f2bf(ts[tx][ty * 16 + i]);
  }
}

// stage one 32KB chunk image with 8 waves: 4 issues x 64 lanes x 16B, linear LDS
__device__ __forceinline__ void stage32k(const ushort* g, ushort* l, int wid, int lane) {
  const ushort* gs = g + wid * 2048 + lane * 8;
  ushort* ls = l + wid * 2048;
#pragma unroll
  for (int i = 0; i < 4; ++i)
    __builtin_amdgcn_global_load_lds(
        (const __attribute__((address_space(1))) void*)(gs + i * 512),
        (__attribute__((address_space(3))) void*)(ls + i * 512), 16, 0, 0);
}

// ---------------- MFMA FFN v10b: round-13 best + b64-merged H-writes ----------------
// 16x16 frags, MTILE=64, 16 waves/CU (2 blocks x 8 waves), single-buffered
// weight staging, 2 barriers/chunk. H-writes merged to uint2 (v11-verified
// byte placement) to halve write instrs and conflicts vs round-13's b32 pairs.
__global__ __launch_bounds__(512, 4) void ffn_mfma10(
    const ushort* __restrict__ xbf, const ushort* __restrict__ w1s,
    const float* __restrict__ b1, const ushort* __restrict__ w2s,
    const float* __restrict__ b2, const int* __restrict__ counts,
    const int* __restrict__ buckets, float* __restrict__ out) {
  const int e = blockIdx.x & 7;       // expert = id%8 -> pins expert weights per-XCD L2
  const int tile = blockIdx.x >> 3;
  const int cnt = min(counts[e], BSTRIDE);
  const int m0 = tile * MTILE;
  if (m0 >= cnt) return;

  __shared__ ushort W1b[CHUNK_US];   // 32KB single-buffered
  __shared__ ushort W2b[CHUNK_US];   // 32KB single-buffered
  __shared__ ushort Hb[4096];        // 8KB: [mt 4][ks 2][lane 64][8] frag-ready

  const int tid = threadIdx.x;
  const int lane = tid & 63;
  const int wid = tid >> 6;           // 0..7
  const int l15 = lane & 15;
  const int q = lane >> 4;            // 0..3
  const int fp = wid >> 2;            // GEMM1: f-pair (kstep) 0..1
  const int mt = wid & 3;             // m-tile 0..3 (both GEMMs)
  const int dh = wid >> 2;            // GEMM2: d-half 0..1

  const ushort* w1g = w1s + (size_t)e * 16 * CHUNK_US;
  const ushort* w2g = w2s + (size_t)e * 16 * CHUNK_US;

  // prologue staging: chunk 0
  stage32k(w1g, W1b, wid, lane);
  stage32k(w2g, W2b, wid, lane);

  // X B-frags for m-tile mt: row m = l15, k = d = 32*dks + 8q + j. 8 x 16B = 32 VGPR.
  const int mxi = m0 + mt * 16 + l15;
  const int tokx = buckets[e * BSTRIDE + (mxi < cnt ? mxi : cnt - 1)];
  const ushort* xp = xbf + (size_t)tokx * DD + q * 8;
  bh8 xf[8];
#pragma unroll
  for (int dks = 0; dks < 8; ++dks)
    xf[dks] = *reinterpret_cast<const bh8*>(xp + dks * 32);

  __syncthreads();                    // prologue staging drained

  f4v yacc[8] = {};                   // 8 d-tiles x 4 f32 = 32 AGPR

#pragma unroll 1
  for (int c = 0; c < 16; ++c) {
    // ---- GEMM1(c): tiles t = 2fp, 2fp+1 for m-tile mt ----
    {
      const char* wb = reinterpret_cast<const char*>(W1b);
      f4v h0 = {}, h1 = {};
      const int fl0 = (2 * fp) * 16 + l15;
      const int fl1 = (2 * fp + 1) * 16 + l15;
#pragma unroll
      for (int dks = 0; dks < 8; ++dks) {
        const int co = (32 * dks + 8 * q) * 2;
        const bh8 a0 = *reinterpret_cast<const bh8*>(
            wb + ((fl0 * 512 + co) ^ ((fl0 & 31) << 4)));
        const bh8 a1 = *reinterpret_cast<const bh8*>(
            wb + ((fl1 * 512 + co) ^ ((fl1 & 31) << 4)));
        h0 = __builtin_amdgcn_mfma_f32_16x16x32_bf16(a0, xf[dks], h0, 0, 0, 0);
        h1 = __builtin_amdgcn_mfma_f32_16x16x32_bf16(a1, xf[dks], h1, 0, 0, 0);
      }
      // bias + relu + scatter-pack into frag-ready Hb.
      // b64 merged write (v11-verified placement): words (2q+0)&3,(2q+1)&3
      // == uint2 @ byte (q&1)<<3 of the 16B fragment.
      char* hbb = reinterpret_cast<char*>(Hb);
#pragma unroll
      for (int th = 0; th < 2; ++th) {
        const int t = 2 * fp + th;
        const float4 bv = *reinterpret_cast<const float4*>(
            b1 + e * FF + c * 64 + t * 16 + 4 * q);
        const f4v& ha = th ? h1 : h0;
        const float v0 = fmaxf(ha[0] + bv.x, 0.f);
        const float v1 = fmaxf(ha[1] + bv.y, 0.f);
        const float v2 = fmaxf(ha[2] + bv.z, 0.f);
        const float v3 = fmaxf(ha[3] + bv.w, 0.f);
        const int laneT = (2 * th + (q >> 1)) * 16 + l15;
        const int base = ((mt * 2 + fp) * 64 + laneT) * 16;
        uint2 wv;
        wv.x = pack2(v0, v1);
        wv.y = pack2(v2, v3);
        *reinterpret_cast<uint2*>(hbb + base + ((q & 1) << 3)) = wv;
      }
    }
    __syncthreads();   // MID: Hb visible; W1b reads done

    if (c < 15)
      stage32k(w1g + (size_t)(c + 1) * CHUNK_US, W1b, wid, lane);  // overlaps GEMM2

    // ---- GEMM2(c): A = Hb frags (dense), B = W2b frags (swizzled) ----
    {
      const char* hbb = reinterpret_cast<const char*>(Hb);
      const char* wb = reinterpret_cast<const char*>(W2b);
#pragma unroll
      for (int ks = 0; ks < 2; ++ks) {
        const bh8 af = *reinterpret_cast<const bh8*>(
            hbb + ((mt * 2 + ks) * 64 + lane) * 16);
        const int co = (32 * ks + 8 * q) * 2;
#pragma unroll
        for (int dt = 0; dt < 8; ++dt) {
          const int d = (dh * 8 + dt) * 16 + l15;
          const bh8 b = *reinterpret_cast<const bh8*>(
              wb + ((d * 128 + co) ^ ((d & 31) << 4)));
          yacc[dt] = __builtin_amdgcn_mfma_f32_16x16x32_bf16(af, b, yacc[dt], 0, 0, 0);
        }
      }
    }
    __syncthreads();   // END: W2b/Hb reads done; w1(c+1) staging drained

    if (c < 15)
      stage32k(w2g + (size_t)(c + 1) * CHUNK_US, W2b, wid, lane);  // overlaps GEMM1(c+1)
  }

  // epilogue: + b2, scatter. D[m][d]: col d = (dh*8+dt)*16 + l15, row m = mt*16 + 4q + r.
  int toks4[4];
#pragma unroll
  for (int r = 0; r < 4; ++r) {
    const int m = m0 + mt * 16 + 4 * q + r;
    toks4[r] = buckets[e * BSTRIDE + (m < cnt ? m : cnt - 1)];
  }
#pragma unroll
  for (int dt = 0; dt < 8; ++dt) {
    const int d = (dh * 8 + dt) * 16 + l15;
    const float b2v = b2[e * DD + d];
#pragma unroll
    for (int r = 0; r < 4; ++r) {
      const int m = mt * 16 + 4 * q + r;
      if (m0 + m < cnt)
        out[(size_t)toks4[r] * DD + d] = yacc[dt][r] + b2v;
    }
  }
}

// ---------------- fallback fp32 FFN (proven in round 1) ----------------
__global__ __launch_bounds__(512) void ffn_fp32(
    const float* __restrict__ x, const float* __restrict__ w1,
    const float* __restrict__ b1, const float* __restrict__ w2,
    const float* __restrict__ b2, const int* __restrict__ counts,
    const int* __restrict__ buckets, float* __restrict__ out, int bstride) {
  const int e = blockIdx.y;
  const int cnt = min(counts[e], bstride);
  const int m0 = blockIdx.x * 64;
  if (m0 >= cnt) return;

  __shared__ float Xt[DD][64];
  __shared__ float Ht[64][64];
  __shared__ int toks[64];

  const int tid = threadIdx.x;
  if (tid < 64) {
    const int i = m0 + tid;
    toks[tid] = buckets[e * bstride + (i < cnt ? i : cnt - 1)];
  }
  __syncthreads();

  for (int idx = tid; idx < 64 * (DD / 4); idx += 512) {
    const int r = idx >> 6;
    const int c4 = idx & 63;
    const float4 v = *reinterpret_cast<const float4*>(x + (size_t)toks[r] * DD + c4 * 4);
    Xt[c4 * 4 + 0][r] = v.x;
    Xt[c4 * 4 + 1][r] = v.y;
    Xt[c4 * 4 + 2][r] = v.z;
    Xt[c4 * 4 + 3][r] = v.w;
  }
  __syncthreads();

  const int fg = tid & 15;
  const int mg = tid >> 4;
  const int dc = tid & 63;
  const int mgrp = tid >> 6;

  float yacc[8][4];
#pragma unroll
  for (int i = 0; i < 8; ++i)
#pragma unroll
    for (int jj = 0; jj < 4; ++jj) yacc[i][jj] = 0.f;

  for (int fc0 = 0; fc0 < FF; fc0 += 64) {
    float hacc[2][4];
#pragma unroll
    for (int i = 0; i < 2; ++i)
#pragma unroll
      for (int jj = 0; jj < 4; ++jj) hacc[i][jj] = 0.f;

    const float* w1p = w1 + (size_t)e * DD * FF + fc0 + fg * 4;
    for (int d = 0; d < DD; ++d) {
      const float4 w = *reinterpret_cast<const float4*>(w1p + (size_t)d * FF);
      const float2 xv = *reinterpret_cast<const float2*>(&Xt[d][mg * 2]);
      const float ws[4] = {w.x, w.y, w.z, w.w};
      const float xl[2] = {xv.x, xv.y};
#pragma unroll
      for (int i = 0; i < 2; ++i)
#pragma unroll
        for (int jj = 0; jj < 4; ++jj)
          hacc[i][jj] = fmaf(xl[i], ws[jj], hacc[i][jj]);
    }
#pragma unroll
    for (int jj = 0; jj < 4; ++jj) {
      const float bb = b1[e * FF + fc0 + fg * 4 + jj];
      Ht[fg * 4 + jj][mg * 2 + 0] = fmaxf(hacc[0][jj] + bb, 0.f);
      Ht[fg * 4 + jj][mg * 2 + 1] = fmaxf(hacc[1][jj] + bb, 0.f);
    }
    __syncthreads();

    const float* w2p = w2 + (size_t)e * FF * DD + (size_t)fc0 * DD + dc * 4;
    for (int f = 0; f < 64; ++f) {
      const float4 w = *reinterpret_cast<const float4*>(w2p + (size_t)f * DD);
      const float4 h0 = *reinterpret_cast<const float4*>(&Ht[f][mgrp * 8]);
      const float4 h1 = *reinterpret_cast<const float4*>(&Ht[f][mgrp * 8 + 4]);
      const float hs[8] = {h0.x, h0.y, h0.z, h0.w, h1.x, h1.y, h1.z, h1.w};
      const float ws[4] = {w.x, w.y, w.z, w.w};
#pragma unroll
      for (int i = 0; i < 8; ++i)
#pragma unroll
        for (int jj = 0; jj < 4; ++jj)
          yacc[i][jj] = fmaf(hs[i], ws[jj], yacc[i][jj]);
    }
    __syncthreads();
  }

#pragma unroll
  for (int i = 0; i < 8; ++i) {
    const int r = mgrp * 8 + i;
    if (m0 + r < cnt) {
      float4 o;
      o.x = yacc[i][0] + b2[e * DD + dc * 4 + 0];
      o.y = yacc[i][1] + b2[e * DD + dc * 4 + 1];
      o.z = yacc[i][2] + b2[e * DD + dc * 4 + 2];
      o.w = yacc[i][3] + b2[e * DD + dc * 4 + 3];
      *reinterpret_cast<float4*>(out + (size_t)toks[r] * DD + dc * 4) = o;
    }
  }
}

extern "C" void kernel_launch(void* const* d_in, const int* in_sizes, int n_in,
                              void* d_out, int out_size, void* d_ws, size_t ws_size,
                              hipStream_t stream) {
  const float* x  = (const float*)d_in[0];
  const float* gw = (const float*)d_in[1];
  const float* gb = (const float*)d_in[2];
  const float* w1 = (const float*)d_in[3];
  const float* b1 = (const float*)d_in[4];
  const float* w2 = (const float*)d_in[5];
  const float* b2 = (const float*)d_in[6];
  float* out = (float*)d_out;

  // ws: counts@0 (4K) | buckets@4K (384K) | w1s@512K (4M) | w2s@4.5M (4M) | xbf@8.5M (32M)
  int* counts = (int*)d_ws;
  int* buckets = (int*)((char*)d_ws + 4096);
  ushort* w1s = (ushort*)((char*)d_ws + 524288);
  ushort* w2s = (ushort*)((char*)d_ws + 524288 + 4194304);
  ushort* xbf = (ushort*)((char*)d_ws + 524288 + 2ull * 4194304);
  const size_t need = 524288 + 2ull * 4194304 + (size_t)NTOK * DD * 2;

  hipMemsetAsync(d_ws, 0, 4096, stream);

  if (ws_size >= need) {
    hipLaunchKernelGGL(gate_route3, dim3(NTOK / 64), dim3(1024), 0, stream,
                       x, gw, gb, counts, buckets, xbf);
    hipLaunchKernelGGL(prep_w1s, dim3(FF / 64, DD / 64, EE), dim3(64, 4), 0, stream,
                       w1, w1s);
    hipLaunchKernelGGL(prep_w2s, dim3(DD / 64, FF / 64, EE), dim3(64, 4), 0, stream,
                       w2, w2s);
    hipLaunchKernelGGL(ffn_mfma10, dim3(NTILES * EE), dim3(512), 0, stream,
                       xbf, w1s, b1, w2s, b2, counts, buckets, out);
  } else {
    hipLaunchKernelGGL(gate_route3, dim3(NTOK / 64), dim3(1024), 0, stream,
                       x, gw, gb, counts, buckets, (ushort*)nullptr);
    hipLaunchKernelGGL(ffn_fp32, dim3(NTOK / 64, EE), dim3(512), 0, stream,
                       x, w1, b1, w2, b2, counts, buckets, out, BSTRIDE);
  }
}